// Round 3
// baseline (638.482 us; speedup 1.0000x reference)
//
#include <hip/hip_runtime.h>

typedef unsigned short u16;
typedef __attribute__((ext_vector_type(8))) short short8;
typedef __attribute__((ext_vector_type(4))) float floatx4;

__device__ __forceinline__ u16 f2bf(float f) {
  unsigned u = __float_as_uint(f);
  u = u + 0x7FFFu + ((u >> 16) & 1u);   // RNE
  return (u16)(u >> 16);
}
__device__ __forceinline__ float bf2f(u16 h) {
  return __uint_as_float(((unsigned)h) << 16);
}

// ---------------- fp32 -> bf16 cast (x4 vectorized) ----------------
__global__ __launch_bounds__(256) void cast_bf16_kernel(const float* __restrict__ in,
                                                        u16* __restrict__ out, int n4) {
  int i = blockIdx.x * 256 + threadIdx.x;
  int stride = gridDim.x * 256;
  for (; i < n4; i += stride) {
    float4 v = reinterpret_cast<const float4*>(in)[i];
    ushort4 o;
    o.x = f2bf(v.x); o.y = f2bf(v.y); o.z = f2bf(v.z); o.w = f2bf(v.w);
    reinterpret_cast<ushort4*>(out)[i] = o;
  }
}

// ---------------- mask normalization: bool-bytes / int32 / float32 -> int32 ----------------
__global__ __launch_bounds__(256) void mask_norm_kernel(const void* __restrict__ mraw,
                                                        int* __restrict__ mout, int n) {
  __shared__ int mode;
  const int t = threadIdx.x;
  const int* mi = (const int*)mraw;
  if (t == 0) mode = 0;
  __syncthreads();
  int local = 0;
  for (int i = t; i < 2048; i += 256) {
    unsigned v = (unsigned)mi[i];
    if (v == 0x3F800000u) { local = 2; break; }
    if (v > 1u) local = 1;
  }
  atomicMax(&mode, local);
  __syncthreads();
  const int m = mode;
  const unsigned char* mb = (const unsigned char*)mraw;
  const float* mf = (const float*)mraw;
  for (int i = t; i < n; i += 256) {
    int v;
    if (m == 1)      v = (int)mb[i];
    else if (m == 2) v = (mf[i] != 0.0f) ? 1 : 0;
    else             v = mi[i];
    mout[i] = v;
  }
}

// ---------------- generic C = epilogue(A @ B^T), bf16 inputs ----------------
// Tile 128x128, BK=32, 4 waves (2x2), each wave 64x64 via 4x4 mfma_16x16x32_bf16.
// EPI: 0 = bf16 store, 1 = fp32 store, 2 = bias+relu -> bf16, 3 = bias -> fp32
template<int EPI>
__global__ __launch_bounds__(256) void gemm_bt(
    const u16* __restrict__ A, const u16* __restrict__ B, void* __restrict__ Cv,
    const float* __restrict__ bias,
    int M, int N, int K, int lda, int ldb, int ldc,
    long aBatch, long bBatch, long cBatch)
{
  __shared__ u16 As[128 * 32];
  __shared__ u16 Bs[128 * 32];
  const int t = threadIdx.x;
  const int l = t & 63;
  const int w = t >> 6;
  const int wr = w >> 1, wc = w & 1;
  const int m0 = blockIdx.y * 128, n0 = blockIdx.x * 128;
  const long z = blockIdx.z;
  const u16* Ab = A + z * aBatch;
  const u16* Bb = B + z * bBatch;

  floatx4 acc[4][4];
#pragma unroll
  for (int m = 0; m < 4; ++m)
#pragma unroll
    for (int n = 0; n < 4; ++n)
      acc[m][n] = (floatx4){0.f, 0.f, 0.f, 0.f};

  const int row_st = t >> 2;       // 0..63
  const int kcol = (t & 3) * 8;    // k element offset of this thread's 16B chunk

  for (int kt = 0; kt < K; kt += 32) {
#pragma unroll
    for (int c = 0; c < 2; ++c) {
      int rA = m0 + c * 64 + row_st; if (rA >= M) rA = M - 1;
      int rB = n0 + c * 64 + row_st; if (rB >= N) rB = N - 1;
      int li = (c * 256 + t) * 8;  // u16 index into LDS (linear, lane*16B per wave)
      __builtin_amdgcn_global_load_lds(
          (const __attribute__((address_space(1))) void*)(Ab + (long)rA * lda + kt + kcol),
          (__attribute__((address_space(3))) void*)(As + li), 16, 0, 0);
      __builtin_amdgcn_global_load_lds(
          (const __attribute__((address_space(1))) void*)(Bb + (long)rB * ldb + kt + kcol),
          (__attribute__((address_space(3))) void*)(Bs + li), 16, 0, 0);
    }
    __syncthreads();  // compiler drains vmcnt before s_barrier

    short8 af[4], bf[4];
#pragma unroll
    for (int m = 0; m < 4; ++m)
      af[m] = *reinterpret_cast<const short8*>(&As[(wr * 64 + m * 16 + (l & 15)) * 32 + (l >> 4) * 8]);
#pragma unroll
    for (int n = 0; n < 4; ++n)
      bf[n] = *reinterpret_cast<const short8*>(&Bs[(wc * 64 + n * 16 + (l & 15)) * 32 + (l >> 4) * 8]);

#pragma unroll
    for (int m = 0; m < 4; ++m)
#pragma unroll
      for (int n = 0; n < 4; ++n)
        acc[m][n] = __builtin_amdgcn_mfma_f32_16x16x32_bf16(af[m], bf[n], acc[m][n], 0, 0, 0);

    __syncthreads();  // all frag reads done before next staging overwrites LDS
  }

  const int cr = (l >> 4) * 4;  // C row sub-index
  const int cc = l & 15;        // C col sub-index
#pragma unroll
  for (int m = 0; m < 4; ++m) {
#pragma unroll
    for (int j = 0; j < 4; ++j) {
      int row = m0 + wr * 64 + m * 16 + cr + j;
      if (row < M) {
#pragma unroll
        for (int n = 0; n < 4; ++n) {
          int col = n0 + wc * 64 + n * 16 + cc;
          if (col < N) {
            float v = acc[m][n][j];
            long idx = z * cBatch + (long)row * ldc + col;
            if constexpr (EPI == 0) {
              ((u16*)Cv)[idx] = f2bf(v);
            } else if constexpr (EPI == 1) {
              ((float*)Cv)[idx] = v;
            } else if constexpr (EPI == 2) {
              v += bias[col]; v = fmaxf(v, 0.f);
              ((u16*)Cv)[idx] = f2bf(v);
            } else {
              v += bias[col];
              ((float*)Cv)[idx] = v;
            }
          }
        }
      }
    }
  }
}

// ---------------- masked softmax over rows of 2048, in-place on bf16 ----------------
__global__ __launch_bounds__(256) void softmax_mask_kernel(u16* __restrict__ P,
                                                           const int* __restrict__ mask) {
  __shared__ float red[8];
  const long row = blockIdx.x;  // h*V + q
  u16* p = P + row * 2048;
  const int t = threadIdx.x;
  float lv[8];
  float mx = -3.0e38f;
#pragma unroll
  for (int j = 0; j < 8; ++j) {
    int s = t + j * 256;
    float v = mask[s] ? -3.0e38f : bf2f(p[s]) * 0.125f;  // scale = 1/sqrt(64)
    lv[j] = v; mx = fmaxf(mx, v);
  }
#pragma unroll
  for (int o = 32; o; o >>= 1) mx = fmaxf(mx, __shfl_xor(mx, o));
  if ((t & 63) == 0) red[t >> 6] = mx;
  __syncthreads();
  mx = fmaxf(fmaxf(red[0], red[1]), fmaxf(red[2], red[3]));
  float sum = 0.f;
#pragma unroll
  for (int j = 0; j < 8; ++j) {
    float e = __expf(lv[j] - mx);
    lv[j] = e; sum += e;
  }
#pragma unroll
  for (int o = 32; o; o >>= 1) sum += __shfl_xor(sum, o);
  if ((t & 63) == 0) red[4 + (t >> 6)] = sum;
  __syncthreads();
  sum = red[4] + red[5] + red[6] + red[7];
  float inv = 1.0f / sum;
#pragma unroll
  for (int j = 0; j < 8; ++j) {
    int s = t + j * 256;
    p[s] = f2bf(lv[j] * inv);
  }
}

// ---------------- residual + layernorm (row = 512), one wave per row ----------------
// Always writes fp32 `xf`; optionally also writes bf16 copy `xb` (for FF1 input).
template<bool WRITE_BF>
__global__ __launch_bounds__(64) void ln_kernel(const float* __restrict__ r1,
    const float* __restrict__ r2, const float* __restrict__ g, const float* __restrict__ be,
    float* __restrict__ xf, u16* __restrict__ xb) {
  const long base = (long)blockIdx.x * 512;
  const int t = threadIdx.x;
  float v[8]; float s = 0.f;
#pragma unroll
  for (int j = 0; j < 8; ++j) { int i = t + j * 64; v[j] = r1[base + i] + r2[base + i]; s += v[j]; }
#pragma unroll
  for (int o = 32; o; o >>= 1) s += __shfl_xor(s, o);
  const float mu = s * (1.0f / 512.0f);
  float q = 0.f;
#pragma unroll
  for (int j = 0; j < 8; ++j) { float d = v[j] - mu; q += d * d; }
#pragma unroll
  for (int o = 32; o; o >>= 1) q += __shfl_xor(q, o);
  const float rs = rsqrtf(q * (1.0f / 512.0f) + 1e-5f);
#pragma unroll
  for (int j = 0; j < 8; ++j) {
    int i = t + j * 64;
    float o = (v[j] - mu) * rs * g[i] + be[i];
    xf[base + i] = o;
    if (WRITE_BF) xb[base + i] = f2bf(o);
  }
}

// ---------------- V transpose: Vt[b][h][d][s] = KV[b*S+s][512 + h*64 + d] ----------------
__global__ __launch_bounds__(256) void transpose_v_kernel(const u16* __restrict__ KV,
                                                          u16* __restrict__ Vt) {
  __shared__ u16 tile[128 * 65];  // +1 row pad to break bank conflicts on read
  const int z = blockIdx.y;       // b*8 + h
  const int b = z >> 3, h = z & 7;
  const int s0 = blockIdx.x * 128;
  const int t = threadIdx.x;
#pragma unroll
  for (int k = 0; k < 32; ++k) {
    int i = k * 256 + t;
    int s = i >> 6, d = i & 63;
    tile[s * 65 + d] = KV[(long)(b * 2048 + s0 + s) * 1024 + 512 + h * 64 + d];
  }
  __syncthreads();
#pragma unroll
  for (int k = 0; k < 32; ++k) {
    int i = k * 256 + t;
    int d = i >> 7, sl = i & 127;
    Vt[((long)z * 64 + d) * 2048 + s0 + sl] = tile[sl * 65 + d];
  }
}

extern "C" void kernel_launch(void* const* d_in, const int* in_sizes, int n_in,
                              void* d_out, int out_size, void* d_ws, size_t ws_size,
                              hipStream_t stream) {
  const float* tgt    = (const float*)d_in[0];
  const float* memory = (const float*)d_in[1];
  const void*  maskraw= (const void*)d_in[2];
  const float* Wq  = (const float*)d_in[3];
  const float* Wkv = (const float*)d_in[4];
  const float* Wo  = (const float*)d_in[5];
  const float* W1  = (const float*)d_in[6];
  const float* b1  = (const float*)d_in[7];
  const float* W2  = (const float*)d_in[8];
  const float* b2  = (const float*)d_in[9];
  const float* g1  = (const float*)d_in[10];
  const float* be1 = (const float*)d_in[11];
  const float* g2  = (const float*)d_in[12];
  const float* be2 = (const float*)d_in[13];

  constexpr int B = 4, V = 1024, S = 2048, D = 512, H = 8, FF = 2048, hd = 64;

  char* p = (char*)d_ws;
  auto alloc = [&](size_t bytes) -> void* {
    void* r = (void*)p; p += (bytes + 255) & ~(size_t)255; return r;
  };
  u16*  tgt_b = (u16*)alloc((size_t)B * V * D * 2);
  u16*  mem_b = (u16*)alloc((size_t)B * S * D * 2);
  u16*  wq_b  = (u16*)alloc((size_t)D * D * 2);
  u16*  wkv_b = (u16*)alloc((size_t)2 * D * D * 2);
  u16*  wo_b  = (u16*)alloc((size_t)D * D * 2);
  u16*  w1_b  = (u16*)alloc((size_t)FF * D * 2);
  u16*  w2_b  = (u16*)alloc((size_t)D * FF * 2);
  u16*  Qb    = (u16*)alloc((size_t)B * V * D * 2);
  u16*  KVb   = (u16*)alloc((size_t)B * S * 2 * D * 2);
  u16*  Vt    = (u16*)alloc((size_t)B * H * hd * S * 2);
  u16*  Pb    = (u16*)alloc((size_t)H * V * S * 2);   // per-b scores/probs, reused
  u16*  attn_b= (u16*)alloc((size_t)B * V * D * 2);
  float* proj = (float*)alloc((size_t)B * V * D * 4);
  float* xf   = (float*)alloc((size_t)B * V * D * 4);
  u16*  xb    = (u16*)alloc((size_t)B * V * D * 2);
  u16*  hb    = (u16*)alloc((size_t)B * V * FF * 2);
  float* ffb  = (float*)alloc((size_t)B * V * D * 4);
  int*  maskI = (int*)alloc((size_t)B * S * 4);

  auto cast = [&](const float* src, u16* dst, long n) {
    int n4 = (int)(n / 4);
    int grid = (n4 + 255) / 256; if (grid > 2048) grid = 2048; if (grid < 1) grid = 1;
    cast_bf16_kernel<<<dim3(grid), dim3(256), 0, stream>>>(src, dst, n4);
  };
  cast(tgt, tgt_b, (long)B * V * D);
  cast(memory, mem_b, (long)B * S * D);
  cast(Wq, wq_b, (long)D * D);
  cast(Wkv, wkv_b, (long)2 * D * D);
  cast(Wo, wo_b, (long)D * D);
  cast(W1, w1_b, (long)FF * D);
  cast(W2, w2_b, (long)D * FF);

  mask_norm_kernel<<<dim3(1), 256, 0, stream>>>(maskraw, maskI, B * S);

  // Q = tgt @ Wq^T : (4096,512)x(512,512)
  gemm_bt<0><<<dim3(D / 128, (B * V) / 128, 1), 256, 0, stream>>>(
      tgt_b, wq_b, Qb, nullptr, B * V, D, D, D, D, D, 0, 0, 0);
  // KV = memory @ Wkv^T : (8192,512)x(1024,512)
  gemm_bt<0><<<dim3((2 * D) / 128, (B * S) / 128, 1), 256, 0, stream>>>(
      mem_b, wkv_b, KVb, nullptr, B * S, 2 * D, D, D, D, 2 * D, 0, 0, 0);
  // Vt[b][h][d][s]
  transpose_v_kernel<<<dim3(S / 128, B * H), 256, 0, stream>>>(KVb, Vt);

  for (int b = 0; b < B; ++b) {
    // scores[h][q][s] = Q_h @ K_h^T  (M=1024, N=2048, K=64), batched over h
    gemm_bt<0><<<dim3(S / 128, V / 128, H), 256, 0, stream>>>(
        Qb + (long)b * V * D, KVb + (long)b * S * 2 * D, Pb, nullptr,
        V, S, hd, D, 2 * D, S, (long)hd, (long)hd, (long)V * S);
    // masked softmax in place
    softmax_mask_kernel<<<dim3(H * V), 256, 0, stream>>>(Pb, maskI + b * S);
    // attn[q][h*64+d] = P_h @ V_h (M=1024, N=64, K=2048), batched over h
    gemm_bt<0><<<dim3(1, V / 128, H), 256, 0, stream>>>(
        Pb, Vt + (long)b * H * hd * S, attn_b + (long)b * V * D, nullptr,
        V, hd, S, S, S, D, (long)V * S, (long)hd * S, (long)hd);
  }

  // proj = attn @ Wo^T (fp32 out)
  gemm_bt<1><<<dim3(D / 128, (B * V) / 128, 1), 256, 0, stream>>>(
      attn_b, wo_b, proj, nullptr, B * V, D, D, D, D, D, 0, 0, 0);
  // x = LN(tgt + proj) -> xf (fp32) + xb (bf16)
  ln_kernel<true><<<dim3(B * V), 64, 0, stream>>>(tgt, proj, g1, be1, xf, xb);
  // h = relu(x @ W1^T + b1)
  gemm_bt<2><<<dim3(FF / 128, (B * V) / 128, 1), 256, 0, stream>>>(
      xb, w1_b, hb, b1, B * V, FF, D, D, D, FF, 0, 0, 0);
  // ff = h @ W2^T + b2 (fp32 out)
  gemm_bt<3><<<dim3(D / 128, (B * V) / 128, 1), 256, 0, stream>>>(
      hb, w2_b, ffb, b2, B * V, D, FF, FF, FF, D, 0, 0, 0);
  // out = LN(x + ff) -> fp32 d_out (reference output dtype is float32!)
  ln_kernel<false><<<dim3(B * V), 64, 0, stream>>>(xf, ffb, g2, be2, (float*)d_out, nullptr);
}

// Round 4
// 376.535 us; speedup vs baseline: 1.6957x; 1.6957x over previous
//
#include <hip/hip_runtime.h>

typedef unsigned short u16;
typedef __attribute__((ext_vector_type(8))) short short8;
typedef __attribute__((ext_vector_type(4))) float floatx4;

__device__ __forceinline__ u16 f2bf(float f) {
  unsigned u = __float_as_uint(f);
  u = u + 0x7FFFu + ((u >> 16) & 1u);   // RNE
  return (u16)(u >> 16);
}
__device__ __forceinline__ float bf2f(u16 h) {
  return __uint_as_float(((unsigned)h) << 16);
}

// ---------------- fp32 -> bf16 cast (x4 vectorized) ----------------
__global__ __launch_bounds__(256) void cast_bf16_kernel(const float* __restrict__ in,
                                                        u16* __restrict__ out, int n4) {
  int i = blockIdx.x * 256 + threadIdx.x;
  int stride = gridDim.x * 256;
  for (; i < n4; i += stride) {
    float4 v = reinterpret_cast<const float4*>(in)[i];
    ushort4 o;
    o.x = f2bf(v.x); o.y = f2bf(v.y); o.z = f2bf(v.z); o.w = f2bf(v.w);
    reinterpret_cast<ushort4*>(out)[i] = o;
  }
}

// ---------------- mask normalization: bool-bytes / int32 / float32 -> int32 ----------------
__global__ __launch_bounds__(256) void mask_norm_kernel(const void* __restrict__ mraw,
                                                        int* __restrict__ mout, int n) {
  __shared__ int mode;
  const int t = threadIdx.x;
  const int* mi = (const int*)mraw;
  if (t == 0) mode = 0;
  __syncthreads();
  int local = 0;
  for (int i = t; i < 2048; i += 256) {
    unsigned v = (unsigned)mi[i];
    if (v == 0x3F800000u) { local = 2; break; }
    if (v > 1u) local = 1;
  }
  atomicMax(&mode, local);
  __syncthreads();
  const int m = mode;
  const unsigned char* mb = (const unsigned char*)mraw;
  const float* mf = (const float*)mraw;
  for (int i = t; i < n; i += 256) {
    int v;
    if (m == 1)      v = (int)mb[i];
    else if (m == 2) v = (mf[i] != 0.0f) ? 1 : 0;
    else             v = mi[i];
    mout[i] = v;
  }
}

// ---------------- generic C = epilogue(A @ B^T), bf16 inputs ----------------
// Tile 128x128, BK=32, 4 waves (2x2), each wave 64x64 via 4x4 mfma_16x16x32_bf16.
// EPI: 0 = bf16 store, 1 = fp32 store, 2 = bias+relu -> bf16, 3 = bias -> fp32
template<int EPI>
__global__ __launch_bounds__(256) void gemm_bt(
    const u16* __restrict__ A, const u16* __restrict__ B, void* __restrict__ Cv,
    const float* __restrict__ bias,
    int M, int N, int K, int lda, int ldb, int ldc,
    long aBatch, long bBatch, long cBatch)
{
  __shared__ u16 As[128 * 32];
  __shared__ u16 Bs[128 * 32];
  const int t = threadIdx.x;
  const int l = t & 63;
  const int w = t >> 6;
  const int wr = w >> 1, wc = w & 1;
  const int m0 = blockIdx.y * 128, n0 = blockIdx.x * 128;
  const long z = blockIdx.z;
  const u16* Ab = A + z * aBatch;
  const u16* Bb = B + z * bBatch;

  floatx4 acc[4][4];
#pragma unroll
  for (int m = 0; m < 4; ++m)
#pragma unroll
    for (int n = 0; n < 4; ++n)
      acc[m][n] = (floatx4){0.f, 0.f, 0.f, 0.f};

  const int row_st = t >> 2;       // 0..63
  const int kcol = (t & 3) * 8;    // k element offset of this thread's 16B chunk

  for (int kt = 0; kt < K; kt += 32) {
#pragma unroll
    for (int c = 0; c < 2; ++c) {
      int rA = m0 + c * 64 + row_st; if (rA >= M) rA = M - 1;
      int rB = n0 + c * 64 + row_st; if (rB >= N) rB = N - 1;
      int li = (c * 256 + t) * 8;
      __builtin_amdgcn_global_load_lds(
          (const __attribute__((address_space(1))) void*)(Ab + (long)rA * lda + kt + kcol),
          (__attribute__((address_space(3))) void*)(As + li), 16, 0, 0);
      __builtin_amdgcn_global_load_lds(
          (const __attribute__((address_space(1))) void*)(Bb + (long)rB * ldb + kt + kcol),
          (__attribute__((address_space(3))) void*)(Bs + li), 16, 0, 0);
    }
    __syncthreads();

    short8 af[4], bf[4];
#pragma unroll
    for (int m = 0; m < 4; ++m)
      af[m] = *reinterpret_cast<const short8*>(&As[(wr * 64 + m * 16 + (l & 15)) * 32 + (l >> 4) * 8]);
#pragma unroll
    for (int n = 0; n < 4; ++n)
      bf[n] = *reinterpret_cast<const short8*>(&Bs[(wc * 64 + n * 16 + (l & 15)) * 32 + (l >> 4) * 8]);

#pragma unroll
    for (int m = 0; m < 4; ++m)
#pragma unroll
      for (int n = 0; n < 4; ++n)
        acc[m][n] = __builtin_amdgcn_mfma_f32_16x16x32_bf16(af[m], bf[n], acc[m][n], 0, 0, 0);

    __syncthreads();
  }

  const int cr = (l >> 4) * 4;
  const int cc = l & 15;
#pragma unroll
  for (int m = 0; m < 4; ++m) {
#pragma unroll
    for (int j = 0; j < 4; ++j) {
      int row = m0 + wr * 64 + m * 16 + cr + j;
      if (row < M) {
#pragma unroll
        for (int n = 0; n < 4; ++n) {
          int col = n0 + wc * 64 + n * 16 + cc;
          if (col < N) {
            float v = acc[m][n][j];
            long idx = z * cBatch + (long)row * ldc + col;
            if constexpr (EPI == 0) {
              ((u16*)Cv)[idx] = f2bf(v);
            } else if constexpr (EPI == 1) {
              ((float*)Cv)[idx] = v;
            } else if constexpr (EPI == 2) {
              v += bias[col]; v = fmaxf(v, 0.f);
              ((u16*)Cv)[idx] = f2bf(v);
            } else {
              v += bias[col];
              ((float*)Cv)[idx] = v;
            }
          }
        }
      }
    }
  }
}

// ---------------- fused flash cross-attention ----------------
// grid (V/128, B*H), block 256 (4 waves, 2x2 over (q, s)).
// Q tile 128x64 staged once (swizzled); per S-tile of 128: K tile (swizzled),
// Vt tile (swizzled), QK^T MFMA, mask+scale, online softmax (cross-wave LDS
// reduce), P -> LDS bf16 (swizzled), PV MFMA into per-wave O accumulator.
// Epilogue: combine wc halves, divide by row sum, write bf16 attn output.
__global__ __launch_bounds__(256, 1) void flash_attn_kernel(
    const u16* __restrict__ Qg, const u16* __restrict__ KVg,
    const u16* __restrict__ Vtg, const int* __restrict__ maskI,
    u16* __restrict__ Og)
{
  __shared__ __align__(16) u16 Qs[128 * 64];
  __shared__ __align__(16) u16 Ks[128 * 64];
  __shared__ __align__(16) u16 Vs[64 * 128];
  __shared__ __align__(16) u16 Ps[128 * 128];
  __shared__ float redA[256];
  __shared__ float redB[256];

  const int t = threadIdx.x;
  const int l = t & 63;
  const int w = t >> 6;
  const int wr = w >> 1, wc = w & 1;
  const int lo = l & 15, hi = l >> 4;
  const int qt = blockIdx.x, bh = blockIdx.y;
  const int b = bh >> 3, h = bh & 7;
  const int q0 = qt * 128;

  const long qbase = ((long)b * 1024 + q0) * 512 + h * 64;   // Q/O element base
  const long kbase = ((long)b * 2048) * 1024 + h * 64;       // K base in KV
  const long vbase = ((long)bh * 64) * 2048;                 // Vt base

  // ---- stage Q tile once: LDS [128 q][64 d], chunk c stored at c^(q&7) ----
#pragma unroll
  for (int j = 0; j < 4; ++j) {
    const int E = (w * 4 + j) * 512;            // wave-uniform LDS element base
    const int q = (w * 4 + j) * 8 + (l >> 3);   // this lane's source row
    const int c = l & 7;
    __builtin_amdgcn_global_load_lds(
        (const __attribute__((address_space(1))) void*)(Qg + qbase + (long)q * 512 + ((c ^ (q & 7)) * 8)),
        (__attribute__((address_space(3))) void*)(Qs + E), 16, 0, 0);
  }
  __syncthreads();

  // ---- Q fragments in registers for the whole kernel ----
  short8 af[4][2];
#pragma unroll
  for (int m = 0; m < 4; ++m)
#pragma unroll
    for (int ks = 0; ks < 2; ++ks) {
      const int q = wr * 64 + m * 16 + lo;
      af[m][ks] = *reinterpret_cast<const short8*>(&Qs[q * 64 + (((ks * 4 + hi) ^ (q & 7)) * 8)]);
    }

  floatx4 accO[4][4];
#pragma unroll
  for (int m = 0; m < 4; ++m)
#pragma unroll
    for (int n = 0; n < 4; ++n)
      accO[4 > m ? m : m][n] = (floatx4){0.f, 0.f, 0.f, 0.f};

  float m_run[4][4], l_run[4][4];
#pragma unroll
  for (int m = 0; m < 4; ++m)
#pragma unroll
    for (int j = 0; j < 4; ++j) { m_run[m][j] = -1.0e30f; l_run[m][j] = 0.f; }

  for (int s0 = 0; s0 < 2048; s0 += 128) {
    // ---- stage K tile [128 s][64 d] (chunk^(s&7)) and Vt tile [64 d][128 s] (chunk^(d&15)) ----
#pragma unroll
    for (int j = 0; j < 4; ++j) {
      const int E = (w * 4 + j) * 512;
      const int s = (w * 4 + j) * 8 + (l >> 3);
      const int ck = l & 7;
      __builtin_amdgcn_global_load_lds(
          (const __attribute__((address_space(1))) void*)(KVg + kbase + (long)(s0 + s) * 1024 + ((ck ^ (s & 7)) * 8)),
          (__attribute__((address_space(3))) void*)(Ks + E), 16, 0, 0);
      const int d = (w * 4 + j) * 4 + (l >> 4);
      const int cv = l & 15;
      __builtin_amdgcn_global_load_lds(
          (const __attribute__((address_space(1))) void*)(Vtg + vbase + (long)d * 2048 + s0 + ((cv ^ (d & 15)) * 8)),
          (__attribute__((address_space(3))) void*)(Vs + E), 16, 0, 0);
    }
    __syncthreads();   // drains vmcnt

    // ---- QK^T: wave computes 64q x 64s ----
    floatx4 sacc[4][4];
#pragma unroll
    for (int m = 0; m < 4; ++m)
#pragma unroll
      for (int n = 0; n < 4; ++n)
        sacc[m][n] = (floatx4){0.f, 0.f, 0.f, 0.f};
    short8 bf[4][2];
#pragma unroll
    for (int n = 0; n < 4; ++n)
#pragma unroll
      for (int ks = 0; ks < 2; ++ks) {
        const int s = wc * 64 + n * 16 + lo;
        bf[n][ks] = *reinterpret_cast<const short8*>(&Ks[s * 64 + (((ks * 4 + hi) ^ (s & 7)) * 8)]);
      }
#pragma unroll
    for (int m = 0; m < 4; ++m)
#pragma unroll
      for (int n = 0; n < 4; ++n)
#pragma unroll
        for (int ks = 0; ks < 2; ++ks)
          sacc[m][n] = __builtin_amdgcn_mfma_f32_16x16x32_bf16(af[m][ks], bf[n][ks], sacc[m][n], 0, 0, 0);

    // ---- scale + mask ----
    int mk[4];
#pragma unroll
    for (int n = 0; n < 4; ++n)
      mk[n] = maskI[b * 2048 + s0 + wc * 64 + n * 16 + lo];
#pragma unroll
    for (int m = 0; m < 4; ++m)
#pragma unroll
      for (int n = 0; n < 4; ++n)
#pragma unroll
        for (int j = 0; j < 4; ++j) {
          float v = sacc[m][n][j] * 0.125f;
          sacc[m][n][j] = mk[n] ? -1.0e30f : v;
        }

    // ---- tile row max (partial over this wave's 64 cols) ----
    float pm[4][4];
#pragma unroll
    for (int m = 0; m < 4; ++m)
#pragma unroll
      for (int j = 0; j < 4; ++j) {
        float v = fmaxf(fmaxf(sacc[m][0][j], sacc[m][1][j]), fmaxf(sacc[m][2][j], sacc[m][3][j]));
        v = fmaxf(v, __shfl_xor(v, 1));
        v = fmaxf(v, __shfl_xor(v, 2));
        v = fmaxf(v, __shfl_xor(v, 4));
        v = fmaxf(v, __shfl_xor(v, 8));
        pm[m][j] = v;
      }
#pragma unroll
    for (int m = 0; m < 4; ++m)
#pragma unroll
      for (int j = 0; j < 4; ++j)
        if (lo == m * 4 + j) redA[wc * 128 + wr * 64 + m * 16 + hi * 4 + j] = pm[m][j];
    __syncthreads();

    // ---- online update: new max, rescale, exp, partial sums, P->LDS ----
    float al[4][4], ps[4][4];
#pragma unroll
    for (int m = 0; m < 4; ++m)
#pragma unroll
      for (int j = 0; j < 4; ++j) {
        const int row = wr * 64 + m * 16 + hi * 4 + j;
        const float tm = fmaxf(redA[row], redA[128 + row]);
        const float mn = fmaxf(m_run[m][j], tm);
        const float a = __expf(m_run[m][j] - mn);
        m_run[m][j] = mn;
        l_run[m][j] *= a;
        al[m][j] = a;
      }
#pragma unroll
    for (int m = 0; m < 4; ++m)
#pragma unroll
      for (int n = 0; n < 4; ++n)
#pragma unroll
        for (int j = 0; j < 4; ++j)
          accO[m][n][j] *= al[m][j];
#pragma unroll
    for (int m = 0; m < 4; ++m)
#pragma unroll
      for (int j = 0; j < 4; ++j) {
        float s = 0.f;
#pragma unroll
        for (int n = 0; n < 4; ++n) {
          float e = __expf(sacc[m][n][j] - m_run[m][j]);
          sacc[m][n][j] = e;
          s += e;
        }
        s += __shfl_xor(s, 1);
        s += __shfl_xor(s, 2);
        s += __shfl_xor(s, 4);
        s += __shfl_xor(s, 8);
        ps[m][j] = s;
      }
#pragma unroll
    for (int m = 0; m < 4; ++m)
#pragma unroll
      for (int j = 0; j < 4; ++j)
        if (lo == m * 4 + j) redB[wc * 128 + wr * 64 + m * 16 + hi * 4 + j] = ps[m][j];
    // P -> LDS bf16, [128 q][128 s], chunk c stored at c^(q&15)
#pragma unroll
    for (int m = 0; m < 4; ++m)
#pragma unroll
      for (int n = 0; n < 4; ++n)
#pragma unroll
        for (int j = 0; j < 4; ++j) {
          const int qr = wr * 64 + m * 16 + hi * 4 + j;
          const int sc = wc * 64 + n * 16 + lo;
          Ps[qr * 128 + (((sc >> 3) ^ (qr & 15)) * 8) + (sc & 7)] = f2bf(sacc[m][n][j]);
        }
    __syncthreads();

#pragma unroll
    for (int m = 0; m < 4; ++m)
#pragma unroll
      for (int j = 0; j < 4; ++j) {
        const int row = wr * 64 + m * 16 + hi * 4 + j;
        l_run[m][j] += redB[row] + redB[128 + row];
      }

    // ---- PV: wave accumulates its s-half (K=64) over all 64 d ----
    short8 pa[4][2], pv[4][2];
#pragma unroll
    for (int m = 0; m < 4; ++m)
#pragma unroll
      for (int ks = 0; ks < 2; ++ks) {
        const int q = wr * 64 + m * 16 + lo;
        pa[m][ks] = *reinterpret_cast<const short8*>(&Ps[q * 128 + (((wc * 8 + ks * 4 + hi) ^ (q & 15)) * 8)]);
      }
#pragma unroll
    for (int n = 0; n < 4; ++n)
#pragma unroll
      for (int ks = 0; ks < 2; ++ks) {
        const int d = n * 16 + lo;
        pv[n][ks] = *reinterpret_cast<const short8*>(&Vs[d * 128 + (((wc * 8 + ks * 4 + hi) ^ (d & 15)) * 8)]);
      }
#pragma unroll
    for (int m = 0; m < 4; ++m)
#pragma unroll
      for (int n = 0; n < 4; ++n)
#pragma unroll
        for (int ks = 0; ks < 2; ++ks)
          accO[m][n] = __builtin_amdgcn_mfma_f32_16x16x32_bf16(pa[m][ks], pv[n][ks], accO[m][n], 0, 0, 0);

    __syncthreads();   // protect Ks/Vs/Ps before next tile overwrites
  }

  // ---- epilogue: combine the two wc halves, normalize, store bf16 ----
  float* Of = (float*)Ps;   // reuse as [128 q][64 d] fp32 (32 KB)
  if (wc == 0) {
#pragma unroll
    for (int m = 0; m < 4; ++m)
#pragma unroll
      for (int n = 0; n < 4; ++n)
#pragma unroll
        for (int j = 0; j < 4; ++j)
          Of[(wr * 64 + m * 16 + hi * 4 + j) * 64 + n * 16 + lo] = accO[m][n][j];
  }
  __syncthreads();
  if (wc == 1) {
#pragma unroll
    for (int m = 0; m < 4; ++m)
#pragma unroll
      for (int j = 0; j < 4; ++j) {
        const int qr = wr * 64 + m * 16 + hi * 4 + j;
        const float inv = 1.0f / l_run[m][j];
#pragma unroll
        for (int n = 0; n < 4; ++n) {
          const int d = n * 16 + lo;
          const float v = (Of[qr * 64 + d] + accO[m][n][j]) * inv;
          Og[qbase + (long)qr * 512 + d] = f2bf(v);
        }
      }
  }
}

// ---------------- residual + 2-way partial sum + optional bias + layernorm ----------------
template<bool WRITE_BF>
__global__ __launch_bounds__(64) void ln3_kernel(const float* __restrict__ r1,
    const float* __restrict__ r2a, const float* __restrict__ r2b,
    const float* __restrict__ bias,
    const float* __restrict__ g, const float* __restrict__ be,
    float* __restrict__ xf, u16* __restrict__ xb) {
  const long base = (long)blockIdx.x * 512;
  const int t = threadIdx.x;
  float v[8]; float s = 0.f;
#pragma unroll
  for (int j = 0; j < 8; ++j) {
    int i = t + j * 64;
    float bv = bias ? bias[i] : 0.f;
    v[j] = r1[base + i] + r2a[base + i] + r2b[base + i] + bv;
    s += v[j];
  }
#pragma unroll
  for (int o = 32; o; o >>= 1) s += __shfl_xor(s, o);
  const float mu = s * (1.0f / 512.0f);
  float q = 0.f;
#pragma unroll
  for (int j = 0; j < 8; ++j) { float d = v[j] - mu; q += d * d; }
#pragma unroll
  for (int o = 32; o; o >>= 1) q += __shfl_xor(q, o);
  const float rs = rsqrtf(q * (1.0f / 512.0f) + 1e-5f);
#pragma unroll
  for (int j = 0; j < 8; ++j) {
    int i = t + j * 64;
    float o = (v[j] - mu) * rs * g[i] + be[i];
    xf[base + i] = o;
    if (WRITE_BF) xb[base + i] = f2bf(o);
  }
}

// ---------------- V transpose: Vt[b][h][d][s] = KV[b*S+s][512 + h*64 + d] ----------------
__global__ __launch_bounds__(256) void transpose_v_kernel(const u16* __restrict__ KV,
                                                          u16* __restrict__ Vt) {
  __shared__ u16 tile[128 * 65];
  const int z = blockIdx.y;
  const int b = z >> 3, h = z & 7;
  const int s0 = blockIdx.x * 128;
  const int t = threadIdx.x;
#pragma unroll
  for (int k = 0; k < 32; ++k) {
    int i = k * 256 + t;
    int s = i >> 6, d = i & 63;
    tile[s * 65 + d] = KV[(long)(b * 2048 + s0 + s) * 1024 + 512 + h * 64 + d];
  }
  __syncthreads();
#pragma unroll
  for (int k = 0; k < 32; ++k) {
    int i = k * 256 + t;
    int d = i >> 7, sl = i & 127;
    Vt[((long)z * 64 + d) * 2048 + s0 + sl] = tile[sl * 65 + d];
  }
}

extern "C" void kernel_launch(void* const* d_in, const int* in_sizes, int n_in,
                              void* d_out, int out_size, void* d_ws, size_t ws_size,
                              hipStream_t stream) {
  const float* tgt    = (const float*)d_in[0];
  const float* memory = (const float*)d_in[1];
  const void*  maskraw= (const void*)d_in[2];
  const float* Wq  = (const float*)d_in[3];
  const float* Wkv = (const float*)d_in[4];
  const float* Wo  = (const float*)d_in[5];
  const float* W1  = (const float*)d_in[6];
  const float* b1  = (const float*)d_in[7];
  const float* W2  = (const float*)d_in[8];
  const float* b2  = (const float*)d_in[9];
  const float* g1  = (const float*)d_in[10];
  const float* be1 = (const float*)d_in[11];
  const float* g2  = (const float*)d_in[12];
  const float* be2 = (const float*)d_in[13];

  constexpr int B = 4, V = 1024, S = 2048, D = 512, H = 8, FF = 2048, hd = 64;

  char* p = (char*)d_ws;
  auto alloc = [&](size_t bytes) -> void* {
    void* r = (void*)p; p += (bytes + 255) & ~(size_t)255; return r;
  };
  u16*  tgt_b = (u16*)alloc((size_t)B * V * D * 2);
  u16*  mem_b = (u16*)alloc((size_t)B * S * D * 2);
  u16*  wq_b  = (u16*)alloc((size_t)D * D * 2);
  u16*  wkv_b = (u16*)alloc((size_t)2 * D * D * 2);
  u16*  wo_b  = (u16*)alloc((size_t)D * D * 2);
  u16*  w1_b  = (u16*)alloc((size_t)FF * D * 2);
  u16*  w2_b  = (u16*)alloc((size_t)D * FF * 2);
  u16*  Qb    = (u16*)alloc((size_t)B * V * D * 2);
  u16*  KVb   = (u16*)alloc((size_t)B * S * 2 * D * 2);
  u16*  Vt    = (u16*)alloc((size_t)B * H * hd * S * 2);
  u16*  attn_b= (u16*)alloc((size_t)B * V * D * 2);
  float* projAB = (float*)alloc((size_t)2 * B * V * D * 4);   // split-K halves
  float* xf   = (float*)alloc((size_t)B * V * D * 4);
  u16*  xb    = (u16*)alloc((size_t)B * V * D * 2);
  u16*  hb    = (u16*)alloc((size_t)B * V * FF * 2);
  float* ffbAB = (float*)alloc((size_t)2 * B * V * D * 4);    // split-K halves
  int*  maskI = (int*)alloc((size_t)B * S * 4);

  auto cast = [&](const float* src, u16* dst, long n) {
    int n4 = (int)(n / 4);
    int grid = (n4 + 255) / 256; if (grid > 2048) grid = 2048; if (grid < 1) grid = 1;
    cast_bf16_kernel<<<dim3(grid), dim3(256), 0, stream>>>(src, dst, n4);
  };
  cast(tgt, tgt_b, (long)B * V * D);
  cast(memory, mem_b, (long)B * S * D);
  cast(Wq, wq_b, (long)D * D);
  cast(Wkv, wkv_b, (long)2 * D * D);
  cast(Wo, wo_b, (long)D * D);
  cast(W1, w1_b, (long)FF * D);
  cast(W2, w2_b, (long)D * FF);

  mask_norm_kernel<<<dim3(1), 256, 0, stream>>>(maskraw, maskI, B * S);

  // Q = tgt @ Wq^T
  gemm_bt<0><<<dim3(D / 128, (B * V) / 128, 1), 256, 0, stream>>>(
      tgt_b, wq_b, Qb, nullptr, B * V, D, D, D, D, D, 0, 0, 0);
  // KV = memory @ Wkv^T
  gemm_bt<0><<<dim3((2 * D) / 128, (B * S) / 128, 1), 256, 0, stream>>>(
      mem_b, wkv_b, KVb, nullptr, B * S, 2 * D, D, D, D, 2 * D, 0, 0, 0);
  // Vt[b][h][d][s]
  transpose_v_kernel<<<dim3(S / 128, B * H), 256, 0, stream>>>(KVb, Vt);

  // fused flash attention -> attn_b (bf16, [B][V][D])
  flash_attn_kernel<<<dim3(V / 128, B * H), 256, 0, stream>>>(
      Qb, KVb, Vt, maskI, attn_b);

  // proj = attn @ Wo^T, split-K z=2 (fp32 halves)
  gemm_bt<1><<<dim3(D / 128, (B * V) / 128, 2), 256, 0, stream>>>(
      attn_b, wo_b, projAB, nullptr, B * V, D, D / 2, D, D, D,
      (long)(D / 2), (long)(D / 2), (long)B * V * D);
  // x = LN(tgt + projA + projB)
  ln3_kernel<true><<<dim3(B * V), 64, 0, stream>>>(
      tgt, projAB, projAB + (long)B * V * D, nullptr, g1, be1, xf, xb);
  // h = relu(x @ W1^T + b1)
  gemm_bt<2><<<dim3(FF / 128, (B * V) / 128, 1), 256, 0, stream>>>(
      xb, w1_b, hb, b1, B * V, FF, D, D, D, FF, 0, 0, 0);
  // ff halves = h @ W2^T, split-K z=2 (b2 added in LN2)
  gemm_bt<1><<<dim3(D / 128, (B * V) / 128, 2), 256, 0, stream>>>(
      hb, w2_b, ffbAB, nullptr, B * V, D, FF / 2, FF, FF, D,
      (long)(FF / 2), (long)(FF / 2), (long)B * V * D);
  // out = LN(x + ffA + ffB + b2) -> fp32 d_out
  ln3_kernel<false><<<dim3(B * V), 64, 0, stream>>>(
      xf, ffbAB, ffbAB + (long)B * V * D, b2, g2, be2, (float*)d_out, nullptr);
}

// Round 5
// 357.390 us; speedup vs baseline: 1.7865x; 1.0536x over previous
//
#include <hip/hip_runtime.h>

typedef unsigned short u16;
typedef __attribute__((ext_vector_type(8))) short short8;
typedef __attribute__((ext_vector_type(4))) float floatx4;

__device__ __forceinline__ u16 f2bf(float f) {
  unsigned u = __float_as_uint(f);
  u = u + 0x7FFFu + ((u >> 16) & 1u);   // RNE
  return (u16)(u >> 16);
}
__device__ __forceinline__ float bf2f(u16 h) {
  return __uint_as_float(((unsigned)h) << 16);
}

// ---------------- fp32 -> bf16 cast (x4 vectorized) ----------------
__global__ __launch_bounds__(256) void cast_bf16_kernel(const float* __restrict__ in,
                                                        u16* __restrict__ out, int n4) {
  int i = blockIdx.x * 256 + threadIdx.x;
  int stride = gridDim.x * 256;
  for (; i < n4; i += stride) {
    float4 v = reinterpret_cast<const float4*>(in)[i];
    ushort4 o;
    o.x = f2bf(v.x); o.y = f2bf(v.y); o.z = f2bf(v.z); o.w = f2bf(v.w);
    reinterpret_cast<ushort4*>(out)[i] = o;
  }
}

// ---------------- mask normalization: bool-bytes / int32 / float32 -> int32 ----------------
__global__ __launch_bounds__(256) void mask_norm_kernel(const void* __restrict__ mraw,
                                                        int* __restrict__ mout, int n) {
  __shared__ int mode;
  const int t = threadIdx.x;
  const int* mi = (const int*)mraw;
  if (t == 0) mode = 0;
  __syncthreads();
  int local = 0;
  for (int i = t; i < 2048; i += 256) {
    unsigned v = (unsigned)mi[i];
    if (v == 0x3F800000u) { local = 2; break; }
    if (v > 1u) local = 1;
  }
  atomicMax(&mode, local);
  __syncthreads();
  const int m = mode;
  const unsigned char* mb = (const unsigned char*)mraw;
  const float* mf = (const float*)mraw;
  for (int i = t; i < n; i += 256) {
    int v;
    if (m == 1)      v = (int)mb[i];
    else if (m == 2) v = (mf[i] != 0.0f) ? 1 : 0;
    else             v = mi[i];
    mout[i] = v;
  }
}

// ---------------- generic C = epilogue(A @ B^T), bf16, double-buffered 2-phase ----------------
// Tile 128x128, BK=32, 4 waves (2x2). One barrier per K-step; next tile's
// global_load_lds issued before compute so the barrier drain is cheap (T3 min).
// EPI: 0 = bf16 store, 1 = fp32 store, 2 = bias+relu -> bf16, 3 = bias -> fp32
template<int EPI>
__global__ __launch_bounds__(256) void gemm_bt(
    const u16* __restrict__ A, const u16* __restrict__ B, void* __restrict__ Cv,
    const float* __restrict__ bias,
    int M, int N, int K, int lda, int ldb, int ldc,
    long aBatch, long bBatch, long cBatch)
{
  __shared__ u16 As[2][128 * 32];
  __shared__ u16 Bs[2][128 * 32];
  const int t = threadIdx.x;
  const int l = t & 63;
  const int w = t >> 6;
  const int wr = w >> 1, wc = w & 1;
  const int m0 = blockIdx.y * 128, n0 = blockIdx.x * 128;
  const long z = blockIdx.z;
  const u16* Ab = A + z * aBatch;
  const u16* Bb = B + z * bBatch;

  floatx4 acc[4][4];
#pragma unroll
  for (int m = 0; m < 4; ++m)
#pragma unroll
    for (int n = 0; n < 4; ++n)
      acc[m][n] = (floatx4){0.f, 0.f, 0.f, 0.f};

  const int row_st = t >> 2;
  const int kcol = (t & 3) * 8;

  auto stage = [&](int buf, int kt) {
#pragma unroll
    for (int c = 0; c < 2; ++c) {
      int rA = m0 + c * 64 + row_st; if (rA >= M) rA = M - 1;
      int rB = n0 + c * 64 + row_st; if (rB >= N) rB = N - 1;
      int li = (c * 256 + t) * 8;
      __builtin_amdgcn_global_load_lds(
          (const __attribute__((address_space(1))) void*)(Ab + (long)rA * lda + kt + kcol),
          (__attribute__((address_space(3))) void*)(As[buf] + li), 16, 0, 0);
      __builtin_amdgcn_global_load_lds(
          (const __attribute__((address_space(1))) void*)(Bb + (long)rB * ldb + kt + kcol),
          (__attribute__((address_space(3))) void*)(Bs[buf] + li), 16, 0, 0);
    }
  };

  stage(0, 0);
  __syncthreads();
  int cur = 0;
  for (int kt = 0; kt < K; kt += 32) {
    if (kt + 32 < K) stage(cur ^ 1, kt + 32);

    short8 af[4], bf[4];
#pragma unroll
    for (int m = 0; m < 4; ++m)
      af[m] = *reinterpret_cast<const short8*>(&As[cur][(wr * 64 + m * 16 + (l & 15)) * 32 + (l >> 4) * 8]);
#pragma unroll
    for (int n = 0; n < 4; ++n)
      bf[n] = *reinterpret_cast<const short8*>(&Bs[cur][(wc * 64 + n * 16 + (l & 15)) * 32 + (l >> 4) * 8]);

    __builtin_amdgcn_s_setprio(1);
#pragma unroll
    for (int m = 0; m < 4; ++m)
#pragma unroll
      for (int n = 0; n < 4; ++n)
        acc[m][n] = __builtin_amdgcn_mfma_f32_16x16x32_bf16(af[m], bf[n], acc[m][n], 0, 0, 0);
    __builtin_amdgcn_s_setprio(0);

    __syncthreads();   // drains next-tile loads (issued before compute) + protects cur swap
    cur ^= 1;
  }

  const int cr = (l >> 4) * 4;
  const int cc = l & 15;
#pragma unroll
  for (int m = 0; m < 4; ++m) {
#pragma unroll
    for (int j = 0; j < 4; ++j) {
      int row = m0 + wr * 64 + m * 16 + cr + j;
      if (row < M) {
#pragma unroll
        for (int n = 0; n < 4; ++n) {
          int col = n0 + wc * 64 + n * 16 + cc;
          if (col < N) {
            float v = acc[m][n][j];
            long idx = z * cBatch + (long)row * ldc + col;
            if constexpr (EPI == 0) {
              ((u16*)Cv)[idx] = f2bf(v);
            } else if constexpr (EPI == 1) {
              ((float*)Cv)[idx] = v;
            } else if constexpr (EPI == 2) {
              v += bias[col]; v = fmaxf(v, 0.f);
              ((u16*)Cv)[idx] = f2bf(v);
            } else {
              v += bias[col];
              ((float*)Cv)[idx] = v;
            }
          }
        }
      }
    }
  }
}

// ---------------- fused flash cross-attention, 8 waves, dbuf K/V, wave-local softmax ----------
// grid (8, 32) remapped XCD-bijectively; block 512 = 8 waves, 2 (q) x 4 (s-slice).
// Per S-tile(128): STAGE(next) -> QK^T (64q x 32s per wave) -> wave-local online
// softmax (private m,l per s-slice) -> P->LDS (same-wave) -> PV (K=32) -> ONE barrier.
// Epilogue merges the 4 s-slices: m*=max, l*=sum(l_i e^{m_i-m*}), O=sum(O_i e^{m_i-m*})/l*.
__global__ __launch_bounds__(512, 2) void flash_attn_kernel(
    const u16* __restrict__ Qg, const u16* __restrict__ KVg,
    const u16* __restrict__ Vtg, const int* __restrict__ maskI,
    u16* __restrict__ Og)
{
  __shared__ __align__(16) u16 Qs[128 * 64];
  __shared__ __align__(16) u16 Ks[2][128 * 64];
  __shared__ __align__(16) u16 Vs[2][64 * 128];
  __shared__ __align__(16) u16 Ps[128 * 128];
  __shared__ float mlred[8][128];

  const int t = threadIdx.x;
  const int l = t & 63;
  const int w = t >> 6;          // 0..7
  const int wr = w >> 2;         // 0..1 : q half
  const int wc = w & 3;          // 0..3 : s quarter
  const int lo = l & 15, hi = l >> 4;

  // XCD-bijective remap: xcd k gets bh in [4k,4k+4) -> K/V (2MB) L2-resident per XCD
  const int id = blockIdx.y * 8 + blockIdx.x;
  const int vid = (id & 7) * 32 + (id >> 3);
  const int qt = vid & 7, bh = vid >> 3;
  const int b = bh >> 3, h = bh & 7;
  const int q0 = qt * 128;

  const long qbase = ((long)b * 1024 + q0) * 512 + h * 64;
  const long kbase = ((long)b * 2048) * 1024 + h * 64;
  const long vbase = ((long)bh * 64) * 2048;

  // ---- preload this lane's mask bits for all 16 tiles (no vmem in main loop) ----
  unsigned mbits = 0;
#pragma unroll
  for (int tt = 0; tt < 16; ++tt)
#pragma unroll
    for (int n = 0; n < 2; ++n)
      mbits |= (maskI[b * 2048 + tt * 128 + wc * 32 + n * 16 + lo] ? 1u : 0u) << (tt * 2 + n);

  // ---- stage Q (swizzled: chunk c of row q at slot c^(q&7)) ----
#pragma unroll
  for (int j = 0; j < 2; ++j) {
    const int ci = j * 512 + t;
    const int q = ci >> 3, c = ci & 7;
    __builtin_amdgcn_global_load_lds(
        (const __attribute__((address_space(1))) void*)(Qg + qbase + (long)q * 512 + ((c ^ (q & 7)) * 8)),
        (__attribute__((address_space(3))) void*)(Qs + ci * 8), 16, 0, 0);
  }

  auto stage_kv = [&](int buf, int soff) {
#pragma unroll
    for (int j = 0; j < 2; ++j) {
      const int ci = j * 512 + t;
      const int ss = ci >> 3, ck = ci & 7;
      __builtin_amdgcn_global_load_lds(
          (const __attribute__((address_space(1))) void*)(KVg + kbase + (long)(soff + ss) * 1024 + ((ck ^ (ss & 7)) * 8)),
          (__attribute__((address_space(3))) void*)(Ks[buf] + ci * 8), 16, 0, 0);
      const int dd = ci >> 4, cv = ci & 15;
      __builtin_amdgcn_global_load_lds(
          (const __attribute__((address_space(1))) void*)(Vtg + vbase + (long)dd * 2048 + soff + ((cv ^ (dd & 15)) * 8)),
          (__attribute__((address_space(3))) void*)(Vs[buf] + ci * 8), 16, 0, 0);
    }
  };

  stage_kv(0, 0);
  __syncthreads();

  // Q fragments live in registers for the whole kernel
  short8 af[4][2];
#pragma unroll
  for (int m = 0; m < 4; ++m)
#pragma unroll
    for (int ks = 0; ks < 2; ++ks) {
      const int q = wr * 64 + m * 16 + lo;
      af[m][ks] = *reinterpret_cast<const short8*>(&Qs[q * 64 + (((ks * 4 + hi) ^ (q & 7)) * 8)]);
    }

  floatx4 accO[4][4];
#pragma unroll
  for (int m = 0; m < 4; ++m)
#pragma unroll
    for (int n = 0; n < 4; ++n)
      accO[m][n] = (floatx4){0.f, 0.f, 0.f, 0.f};
  float m_run[4][4], l_run[4][4];
#pragma unroll
  for (int m = 0; m < 4; ++m)
#pragma unroll
    for (int j = 0; j < 4; ++j) { m_run[m][j] = -1.0e30f; l_run[m][j] = 0.f; }

  int cur = 0;
  for (int s0 = 0; s0 < 2048; s0 += 128) {
    if (s0 + 128 < 2048) stage_kv(cur ^ 1, s0 + 128);

    // ---- QK^T: 64q x 32s per wave ----
    short8 bfr[2][2];
#pragma unroll
    for (int n = 0; n < 2; ++n)
#pragma unroll
      for (int ks = 0; ks < 2; ++ks) {
        const int s = wc * 32 + n * 16 + lo;
        bfr[n][ks] = *reinterpret_cast<const short8*>(&Ks[cur][s * 64 + (((ks * 4 + hi) ^ (s & 7)) * 8)]);
      }
    floatx4 sacc[4][2];
#pragma unroll
    for (int m = 0; m < 4; ++m)
#pragma unroll
      for (int n = 0; n < 2; ++n)
        sacc[m][n] = (floatx4){0.f, 0.f, 0.f, 0.f};
    __builtin_amdgcn_s_setprio(1);
#pragma unroll
    for (int m = 0; m < 4; ++m)
#pragma unroll
      for (int n = 0; n < 2; ++n)
#pragma unroll
        for (int ks = 0; ks < 2; ++ks)
          sacc[m][n] = __builtin_amdgcn_mfma_f32_16x16x32_bf16(af[m][ks], bfr[n][ks], sacc[m][n], 0, 0, 0);
    __builtin_amdgcn_s_setprio(0);

    // ---- scale + mask (sentinel far below m_run init, so exp underflows to 0) ----
    const int sh = s0 >> 6;
#pragma unroll
    for (int n = 0; n < 2; ++n) {
      const bool mk = (mbits >> (sh + n)) & 1u;
#pragma unroll
      for (int m = 0; m < 4; ++m)
#pragma unroll
        for (int j = 0; j < 4; ++j) {
          float v = sacc[m][n][j] * 0.125f;
          sacc[m][n][j] = mk ? -3.0e38f : v;
        }
    }

    // ---- wave-local online softmax over this wave's 32 cols ----
    float al[4][4];
#pragma unroll
    for (int m = 0; m < 4; ++m)
#pragma unroll
      for (int j = 0; j < 4; ++j) {
        float v = fmaxf(sacc[m][0][j], sacc[m][1][j]);
        v = fmaxf(v, __shfl_xor(v, 1));
        v = fmaxf(v, __shfl_xor(v, 2));
        v = fmaxf(v, __shfl_xor(v, 4));
        v = fmaxf(v, __shfl_xor(v, 8));
        const float mn = fmaxf(m_run[m][j], v);
        al[m][j] = __expf(m_run[m][j] - mn);
        m_run[m][j] = mn;
        l_run[m][j] *= al[m][j];
      }
#pragma unroll
    for (int m = 0; m < 4; ++m)
#pragma unroll
      for (int n = 0; n < 4; ++n)
#pragma unroll
        for (int j = 0; j < 4; ++j)
          accO[m][n][j] *= al[m][j];
#pragma unroll
    for (int m = 0; m < 4; ++m)
#pragma unroll
      for (int j = 0; j < 4; ++j) {
        float s = 0.f;
        const int qr = wr * 64 + m * 16 + hi * 4 + j;
#pragma unroll
        for (int n = 0; n < 2; ++n) {
          const float e = __expf(sacc[m][n][j] - m_run[m][j]);
          s += e;
          const int sc = wc * 32 + n * 16 + lo;
          Ps[qr * 128 + (((sc >> 3) ^ (qr & 15)) * 8) + (sc & 7)] = f2bf(e);
        }
        s += __shfl_xor(s, 1);
        s += __shfl_xor(s, 2);
        s += __shfl_xor(s, 4);
        s += __shfl_xor(s, 8);
        l_run[m][j] += s;
      }

    // ---- PV: K=32 (own s-slice); P read is same-wave (no barrier needed) ----
    short8 pa[4], pv[4];
#pragma unroll
    for (int m = 0; m < 4; ++m) {
      const int q = wr * 64 + m * 16 + lo;
      pa[m] = *reinterpret_cast<const short8*>(&Ps[q * 128 + (((wc * 4 + hi) ^ (q & 15)) * 8)]);
    }
#pragma unroll
    for (int n = 0; n < 4; ++n) {
      const int d = n * 16 + lo;
      pv[n] = *reinterpret_cast<const short8*>(&Vs[cur][d * 128 + (((wc * 4 + hi) ^ (d & 15)) * 8)]);
    }
    __builtin_amdgcn_s_setprio(1);
#pragma unroll
    for (int m = 0; m < 4; ++m)
#pragma unroll
      for (int n = 0; n < 4; ++n)
        accO[m][n] = __builtin_amdgcn_mfma_f32_16x16x32_bf16(pa[m], pv[n], accO[m][n], 0, 0, 0);
    __builtin_amdgcn_s_setprio(0);

    __syncthreads();   // the ONE barrier: drains next-tile stage, protects dbuf swap + Ps
    cur ^= 1;
  }

  // ---- epilogue: merge the 4 s-slices ----
  if (lo == 0) {
#pragma unroll
    for (int m = 0; m < 4; ++m)
#pragma unroll
      for (int j = 0; j < 4; ++j) {
        const int row = wr * 64 + m * 16 + hi * 4 + j;
        mlred[wc][row] = m_run[m][j];
        mlred[4 + wc][row] = l_run[m][j];
      }
  }
  __syncthreads();
  float scal[4][4], inv[4][4];
#pragma unroll
  for (int m = 0; m < 4; ++m)
#pragma unroll
    for (int j = 0; j < 4; ++j) {
      const int row = wr * 64 + m * 16 + hi * 4 + j;
      const float m0 = mlred[0][row], m1 = mlred[1][row], m2 = mlred[2][row], m3 = mlred[3][row];
      const float ms = fmaxf(fmaxf(m0, m1), fmaxf(m2, m3));
      const float ls = mlred[4][row] * __expf(m0 - ms) + mlred[5][row] * __expf(m1 - ms)
                     + mlred[6][row] * __expf(m2 - ms) + mlred[7][row] * __expf(m3 - ms);
      scal[m][j] = __expf(m_run[m][j] - ms);
      inv[m][j] = 1.0f / ls;
    }
  float* Of = (float*)Ps;   // reuse as [128 q][64 d] fp32
  if (wc == 0) {
#pragma unroll
    for (int m = 0; m < 4; ++m)
#pragma unroll
      for (int j = 0; j < 4; ++j) {
        const int row = wr * 64 + m * 16 + hi * 4 + j;
#pragma unroll
        for (int n = 0; n < 4; ++n)
          Of[row * 64 + n * 16 + lo] = accO[m][n][j] * scal[m][j];
      }
  }
  __syncthreads();
  if (wc == 1) {
#pragma unroll
    for (int m = 0; m < 4; ++m)
#pragma unroll
      for (int j = 0; j < 4; ++j) {
        const int row = wr * 64 + m * 16 + hi * 4 + j;
#pragma unroll
        for (int n = 0; n < 4; ++n)
          Of[row * 64 + n * 16 + lo] += accO[m][n][j] * scal[m][j];
      }
  }
  __syncthreads();
  if (wc == 2) {
#pragma unroll
    for (int m = 0; m < 4; ++m)
#pragma unroll
      for (int j = 0; j < 4; ++j) {
        const int row = wr * 64 + m * 16 + hi * 4 + j;
#pragma unroll
        for (int n = 0; n < 4; ++n)
          Of[row * 64 + n * 16 + lo] += accO[m][n][j] * scal[m][j];
      }
  }
  __syncthreads();
  if (wc == 3) {
#pragma unroll
    for (int m = 0; m < 4; ++m)
#pragma unroll
      for (int j = 0; j < 4; ++j) {
        const int row = wr * 64 + m * 16 + hi * 4 + j;
#pragma unroll
        for (int n = 0; n < 4; ++n) {
          const int d = n * 16 + lo;
          const float v = (Of[row * 64 + d] + accO[m][n][j] * scal[m][j]) * inv[m][j];
          Og[qbase + (long)row * 512 + d] = f2bf(v);
        }
      }
  }
}

// ---------------- residual + P-way partial sums + optional bias + layernorm ----------------
template<int P, bool WRITE_BF>
__global__ __launch_bounds__(64) void lnp_kernel(const float* __restrict__ r1,
    const float* __restrict__ parts, long pstride,
    const float* __restrict__ bias,
    const float* __restrict__ g, const float* __restrict__ be,
    float* __restrict__ xf, u16* __restrict__ xb) {
  const long base = (long)blockIdx.x * 512;
  const int t = threadIdx.x;
  float v[8]; float s = 0.f;
#pragma unroll
  for (int j = 0; j < 8; ++j) {
    int i = t + j * 64;
    float acc = r1[base + i] + (bias ? bias[i] : 0.f);
#pragma unroll
    for (int q = 0; q < P; ++q) acc += parts[q * pstride + base + i];
    v[j] = acc; s += acc;
  }
#pragma unroll
  for (int o = 32; o; o >>= 1) s += __shfl_xor(s, o);
  const float mu = s * (1.0f / 512.0f);
  float q2 = 0.f;
#pragma unroll
  for (int j = 0; j < 8; ++j) { float d = v[j] - mu; q2 += d * d; }
#pragma unroll
  for (int o = 32; o; o >>= 1) q2 += __shfl_xor(q2, o);
  const float rs = rsqrtf(q2 * (1.0f / 512.0f) + 1e-5f);
#pragma unroll
  for (int j = 0; j < 8; ++j) {
    int i = t + j * 64;
    float o = (v[j] - mu) * rs * g[i] + be[i];
    xf[base + i] = o;
    if (WRITE_BF) xb[base + i] = f2bf(o);
  }
}

// ---------------- V transpose: Vt[b][h][d][s] = KV[b*S+s][512 + h*64 + d] ----------------
__global__ __launch_bounds__(256) void transpose_v_kernel(const u16* __restrict__ KV,
                                                          u16* __restrict__ Vt) {
  __shared__ u16 tile[128 * 65];
  const int z = blockIdx.y;
  const int b = z >> 3, h = z & 7;
  const int s0 = blockIdx.x * 128;
  const int t = threadIdx.x;
#pragma unroll
  for (int k = 0; k < 32; ++k) {
    int i = k * 256 + t;
    int s = i >> 6, d = i & 63;
    tile[s * 65 + d] = KV[(long)(b * 2048 + s0 + s) * 1024 + 512 + h * 64 + d];
  }
  __syncthreads();
#pragma unroll
  for (int k = 0; k < 32; ++k) {
    int i = k * 256 + t;
    int d = i >> 7, sl = i & 127;
    Vt[((long)z * 64 + d) * 2048 + s0 + sl] = tile[sl * 65 + d];
  }
}

extern "C" void kernel_launch(void* const* d_in, const int* in_sizes, int n_in,
                              void* d_out, int out_size, void* d_ws, size_t ws_size,
                              hipStream_t stream) {
  const float* tgt    = (const float*)d_in[0];
  const float* memory = (const float*)d_in[1];
  const void*  maskraw= (const void*)d_in[2];
  const float* Wq  = (const float*)d_in[3];
  const float* Wkv = (const float*)d_in[4];
  const float* Wo  = (const float*)d_in[5];
  const float* W1  = (const float*)d_in[6];
  const float* b1  = (const float*)d_in[7];
  const float* W2  = (const float*)d_in[8];
  const float* b2  = (const float*)d_in[9];
  const float* g1  = (const float*)d_in[10];
  const float* be1 = (const float*)d_in[11];
  const float* g2  = (const float*)d_in[12];
  const float* be2 = (const float*)d_in[13];

  constexpr int B = 4, V = 1024, S = 2048, D = 512, H = 8, FF = 2048, hd = 64;
  const long BVD = (long)B * V * D;

  char* p = (char*)d_ws;
  auto alloc = [&](size_t bytes) -> void* {
    void* r = (void*)p; p += (bytes + 255) & ~(size_t)255; return r;
  };
  u16*  tgt_b = (u16*)alloc((size_t)B * V * D * 2);
  u16*  mem_b = (u16*)alloc((size_t)B * S * D * 2);
  u16*  wq_b  = (u16*)alloc((size_t)D * D * 2);
  u16*  wkv_b = (u16*)alloc((size_t)2 * D * D * 2);
  u16*  wo_b  = (u16*)alloc((size_t)D * D * 2);
  u16*  w1_b  = (u16*)alloc((size_t)FF * D * 2);
  u16*  w2_b  = (u16*)alloc((size_t)D * FF * 2);
  u16*  Qb    = (u16*)alloc((size_t)B * V * D * 2);
  u16*  KVb   = (u16*)alloc((size_t)B * S * 2 * D * 2);
  u16*  Vt    = (u16*)alloc((size_t)B * H * hd * S * 2);
  u16*  attn_b= (u16*)alloc((size_t)B * V * D * 2);
  float* projP = (float*)alloc((size_t)4 * BVD * 4);   // split-K quarters
  float* xf   = (float*)alloc((size_t)BVD * 4);
  u16*  xb    = (u16*)alloc((size_t)BVD * 2);
  u16*  hb    = (u16*)alloc((size_t)B * V * FF * 2);
  float* ffbP = (float*)alloc((size_t)4 * BVD * 4);    // split-K quarters
  int*  maskI = (int*)alloc((size_t)B * S * 4);

  auto cast = [&](const float* src, u16* dst, long n) {
    int n4 = (int)(n / 4);
    int grid = (n4 + 255) / 256; if (grid > 2048) grid = 2048; if (grid < 1) grid = 1;
    cast_bf16_kernel<<<dim3(grid), dim3(256), 0, stream>>>(src, dst, n4);
  };
  cast(tgt, tgt_b, (long)B * V * D);
  cast(memory, mem_b, (long)B * S * D);
  cast(Wq, wq_b, (long)D * D);
  cast(Wkv, wkv_b, (long)2 * D * D);
  cast(Wo, wo_b, (long)D * D);
  cast(W1, w1_b, (long)FF * D);
  cast(W2, w2_b, (long)D * FF);

  mask_norm_kernel<<<dim3(1), 256, 0, stream>>>(maskraw, maskI, B * S);

  // Q = tgt @ Wq^T
  gemm_bt<0><<<dim3(D / 128, (B * V) / 128, 1), 256, 0, stream>>>(
      tgt_b, wq_b, Qb, nullptr, B * V, D, D, D, D, D, 0, 0, 0);
  // KV = memory @ Wkv^T
  gemm_bt<0><<<dim3((2 * D) / 128, (B * S) / 128, 1), 256, 0, stream>>>(
      mem_b, wkv_b, KVb, nullptr, B * S, 2 * D, D, D, D, 2 * D, 0, 0, 0);
  // Vt[b][h][d][s]
  transpose_v_kernel<<<dim3(S / 128, B * H), 256, 0, stream>>>(KVb, Vt);

  // fused flash attention -> attn_b (bf16)
  flash_attn_kernel<<<dim3(8, B * H), 512, 0, stream>>>(
      Qb, KVb, Vt, maskI, attn_b);

  // proj quarters = attn @ Wo^T, split-K z=4 (K=128 each)
  gemm_bt<1><<<dim3(D / 128, (B * V) / 128, 4), 256, 0, stream>>>(
      attn_b, wo_b, projP, nullptr, B * V, D, D / 4, D, D, D,
      (long)(D / 4), (long)(D / 4), BVD);
  // x = LN(tgt + sum proj quarters)
  lnp_kernel<4, true><<<dim3(B * V), 64, 0, stream>>>(
      tgt, projP, BVD, nullptr, g1, be1, xf, xb);
  // h = relu(x @ W1^T + b1)
  gemm_bt<2><<<dim3(FF / 128, (B * V) / 128, 1), 256, 0, stream>>>(
      xb, w1_b, hb, b1, B * V, FF, D, D, D, FF, 0, 0, 0);
  // ff quarters = h @ W2^T, split-K z=4 (K=512 each; b2 added in LN2)
  gemm_bt<1><<<dim3(D / 128, (B * V) / 128, 4), 256, 0, stream>>>(
      hb, w2_b, ffbP, nullptr, B * V, D, FF / 4, FF, FF, D,
      (long)(FF / 4), (long)(FF / 4), BVD);
  // out = LN(x + sum ff quarters + b2) -> fp32 d_out
  lnp_kernel<4, false><<<dim3(B * V), 64, 0, stream>>>(
      xf, ffbP, BVD, b2, g2, be2, (float*)d_out, nullptr);
}

// Round 6
// 302.824 us; speedup vs baseline: 2.1084x; 1.1802x over previous
//
#include <hip/hip_runtime.h>
#include <hip/hip_bf16.h>

typedef unsigned short u16;
typedef __attribute__((ext_vector_type(8))) short short8;
typedef __attribute__((ext_vector_type(4))) float floatx4;

#define AS1 __attribute__((address_space(1)))
#define AS3 __attribute__((address_space(3)))

__device__ __forceinline__ u16 f2bf(float f) {
  unsigned u = __float_as_uint(f);
  u = u + 0x7FFFu + ((u >> 16) & 1u);   // RNE
  return (u16)(u >> 16);
}
__device__ __forceinline__ unsigned pack_bf2(float a, float b) {
  return (unsigned)f2bf(a) | ((unsigned)f2bf(b) << 16);
}

// ---------------- fp32 -> bf16 cast (x4 vectorized) ----------------
__global__ __launch_bounds__(256) void cast_bf16_kernel(const float* __restrict__ in,
                                                        u16* __restrict__ out, int n4) {
  int i = blockIdx.x * 256 + threadIdx.x;
  int stride = gridDim.x * 256;
  for (; i < n4; i += stride) {
    float4 v = reinterpret_cast<const float4*>(in)[i];
    ushort4 o;
    o.x = f2bf(v.x); o.y = f2bf(v.y); o.z = f2bf(v.z); o.w = f2bf(v.w);
    reinterpret_cast<ushort4*>(out)[i] = o;
  }
}

// ---------------- mask -> packed bits (bool-bytes / int32 / float32 tolerated) ----------------
__global__ __launch_bounds__(256) void mask_bits_kernel(const void* __restrict__ mraw,
                                                        unsigned* __restrict__ mout, int n) {
  __shared__ int mode;
  const int t = threadIdx.x;
  const int* mi = (const int*)mraw;
  if (t == 0) mode = 0;
  __syncthreads();
  int local = 0;
  for (int i = t; i < 2048; i += 256) {
    unsigned v = (unsigned)mi[i];
    if (v == 0x3F800000u) { local = 2; break; }
    if (v > 1u) local = 1;
  }
  atomicMax(&mode, local);
  __syncthreads();
  const int m = mode;
  const unsigned char* mb = (const unsigned char*)mraw;
  const float* mf = (const float*)mraw;
  // word wk covers s = wk*32 .. wk*32+31
  for (int wk = t; wk < n / 32; wk += 256) {
    unsigned bits = 0;
    for (int i = 0; i < 32; ++i) {
      int s = wk * 32 + i;
      int v;
      if (m == 1)      v = (int)mb[s];
      else if (m == 2) v = (mf[s] != 0.0f) ? 1 : 0;
      else             v = mi[s];
      bits |= (v ? 1u : 0u) << i;
    }
    mout[wk] = bits;
  }
}

// ---------------- generic C = epilogue(A @ B^T), bf16, double-buffered 2-phase ----------------
template<int EPI>
__global__ __launch_bounds__(256) void gemm_bt(
    const u16* __restrict__ A, const u16* __restrict__ B, void* __restrict__ Cv,
    const float* __restrict__ bias,
    int M, int N, int K, int lda, int ldb, int ldc,
    long aBatch, long bBatch, long cBatch)
{
  __shared__ u16 As[2][128 * 32];
  __shared__ u16 Bs[2][128 * 32];
  const int t = threadIdx.x;
  const int l = t & 63;
  const int w = t >> 6;
  const int wr = w >> 1, wc = w & 1;
  const int m0 = blockIdx.y * 128, n0 = blockIdx.x * 128;
  const long z = blockIdx.z;
  const u16* Ab = A + z * aBatch;
  const u16* Bb = B + z * bBatch;

  floatx4 acc[4][4];
#pragma unroll
  for (int m = 0; m < 4; ++m)
#pragma unroll
    for (int n = 0; n < 4; ++n)
      acc[m][n] = (floatx4){0.f, 0.f, 0.f, 0.f};

  const int row_st = t >> 2;
  const int kcol = (t & 3) * 8;

  auto stage = [&](int buf, int kt) {
#pragma unroll
    for (int c = 0; c < 2; ++c) {
      int rA = m0 + c * 64 + row_st; if (rA >= M) rA = M - 1;
      int rB = n0 + c * 64 + row_st; if (rB >= N) rB = N - 1;
      int li = (c * 256 + t) * 8;
      __builtin_amdgcn_global_load_lds(
          (const AS1 void*)(Ab + (long)rA * lda + kt + kcol),
          (AS3 void*)(As[buf] + li), 16, 0, 0);
      __builtin_amdgcn_global_load_lds(
          (const AS1 void*)(Bb + (long)rB * ldb + kt + kcol),
          (AS3 void*)(Bs[buf] + li), 16, 0, 0);
    }
  };

  stage(0, 0);
  __syncthreads();
  int cur = 0;
  for (int kt = 0; kt < K; kt += 32) {
    if (kt + 32 < K) stage(cur ^ 1, kt + 32);

    short8 af[4], bf[4];
#pragma unroll
    for (int m = 0; m < 4; ++m)
      af[m] = *reinterpret_cast<const short8*>(&As[cur][(wr * 64 + m * 16 + (l & 15)) * 32 + (l >> 4) * 8]);
#pragma unroll
    for (int n = 0; n < 4; ++n)
      bf[n] = *reinterpret_cast<const short8*>(&Bs[cur][(wc * 64 + n * 16 + (l & 15)) * 32 + (l >> 4) * 8]);

    __builtin_amdgcn_s_setprio(1);
#pragma unroll
    for (int m = 0; m < 4; ++m)
#pragma unroll
      for (int n = 0; n < 4; ++n)
        acc[m][n] = __builtin_amdgcn_mfma_f32_16x16x32_bf16(af[m], bf[n], acc[m][n], 0, 0, 0);
    __builtin_amdgcn_s_setprio(0);

    __syncthreads();
    cur ^= 1;
  }

  const int cr = (l >> 4) * 4;
  const int cc = l & 15;
#pragma unroll
  for (int m = 0; m < 4; ++m) {
#pragma unroll
    for (int j = 0; j < 4; ++j) {
      int row = m0 + wr * 64 + m * 16 + cr + j;
      if (row < M) {
#pragma unroll
        for (int n = 0; n < 4; ++n) {
          int col = n0 + wc * 64 + n * 16 + cc;
          if (col < N) {
            float v = acc[m][n][j];
            long idx = z * cBatch + (long)row * ldc + col;
            if constexpr (EPI == 0) {
              ((u16*)Cv)[idx] = f2bf(v);
            } else if constexpr (EPI == 1) {
              ((float*)Cv)[idx] = v;
            } else if constexpr (EPI == 2) {
              v += bias[col]; v = fmaxf(v, 0.f);
              ((u16*)Cv)[idx] = f2bf(v);
            } else {
              v += bias[col];
              ((float*)Cv)[idx] = v;
            }
          }
        }
      }
    }
  }
}

// ---------------- fused flash cross-attention v3 (swapped-operand MFMA) ----------------
// grid (8, 32) XCD-remapped, block 512 = 8 waves = 4 q-quarters (wr) x 2 s-halves (wc).
// S-tile 64. St = mfma(K,Q) -> col=q=lo (softmax lane-local); PV = mfma(V,P) -> col=q=lo.
// P per-wave private LDS slab (b64-vectorized, swizzled). One barrier per tile.
// LDS ~50KB -> 3 blocks/CU.
__global__ __launch_bounds__(512, 4) void flash_attn_kernel(
    const u16* __restrict__ Qg, const u16* __restrict__ KVg,
    const u16* __restrict__ Vtg, const unsigned* __restrict__ mbits,
    u16* __restrict__ Og)
{
  __shared__ __align__(16) u16 KVbuf[2][2][64 * 64];  // [buf][K/V][...], 32 KB
  __shared__ __align__(16) u16 Ps[8][32 * 32];        // per-wave P slab, 16 KB
  __shared__ float mlred[2][2][128];                  // [wc][m|l][q], 2 KB
  __shared__ unsigned mw[64];                         // mask bits for this b

  const int t = threadIdx.x;
  const int l = t & 63;
  const int w = t >> 6;        // 0..7
  const int wr = w >> 1;       // 0..3 : q quarter (32 rows)
  const int wc = w & 1;        // 0..1 : s half (32 cols)
  const int lo = l & 15, hi = l >> 4;

  const int id = blockIdx.y * 8 + blockIdx.x;
  const int vid = (id & 7) * 32 + (id >> 3);
  const int qt = vid & 7, bh = vid >> 3;
  const int b = bh >> 3, h = bh & 7;

  const long qbase = ((long)b * 1024 + qt * 128) * 512 + h * 64;
  const long kbase = ((long)b * 2048) * 1024 + h * 64;
  const long vbase = ((long)bh * 64) * 2048;

  if (t < 64) mw[t] = mbits[b * 64 + t];

  auto stage_kv = [&](int buf, int soff) {
    const int s = t >> 3, c = t & 7;
    __builtin_amdgcn_global_load_lds(
        (const AS1 void*)(KVg + kbase + (long)(soff + s) * 1024 + ((c ^ (s & 7)) * 8)),
        (AS3 void*)(&KVbuf[buf][0][t * 8]), 16, 0, 0);
    __builtin_amdgcn_global_load_lds(
        (const AS1 void*)(Vtg + vbase + (long)s * 2048 + soff + ((c ^ (s & 7)) * 8)),
        (AS3 void*)(&KVbuf[buf][1][t * 8]), 16, 0, 0);
  };

  stage_kv(0, 0);

  // Q fragments: global -> registers, once (L2-resident; one-time cost)
  short8 af[2][2];   // [qm][ks]; B-frag: row=q=lo, k = ks*32 + hi*8 + j
#pragma unroll
  for (int qm = 0; qm < 2; ++qm)
#pragma unroll
    for (int ks = 0; ks < 2; ++ks)
      af[qm][ks] = *reinterpret_cast<const short8*>(
          Qg + qbase + (long)(wr * 32 + qm * 16 + lo) * 512 + ks * 32 + hi * 8);

  __syncthreads();

  floatx4 accO[4][2];   // [dn][qm]: row d = dn*16+hi*4+j, col q = qm*16+lo
#pragma unroll
  for (int dn = 0; dn < 4; ++dn)
#pragma unroll
    for (int qm = 0; qm < 2; ++qm)
      accO[dn][qm] = (floatx4){0.f, 0.f, 0.f, 0.f};
  float m_run[2] = {-1.0e30f, -1.0e30f};
  float l_run[2] = {0.f, 0.f};

  int cur = 0;
  for (int it = 0; it < 32; ++it) {
    const int s0 = it * 64;
    if (it + 1 < 32) stage_kv(cur ^ 1, s0 + 64);

    // ---- St = mfma(K, Q): D[s][q], per wave 32s x 32q ----
    short8 bfr[2][2];   // K A-frag [sn][ks]: row s = wc*32+sn*16+lo, k = ks*32+hi*8+j
#pragma unroll
    for (int sn = 0; sn < 2; ++sn)
#pragma unroll
      for (int ks = 0; ks < 2; ++ks) {
        const int srow = wc * 32 + sn * 16 + lo;
        bfr[sn][ks] = *reinterpret_cast<const short8*>(
            &KVbuf[cur][0][srow * 64 + (((ks * 4 + hi) ^ (lo & 7)) * 8)]);
      }
    floatx4 sacc[2][2];   // [sn][qm]: row s = sn*16+hi*4+j (wave-local), col q = qm*16+lo
#pragma unroll
    for (int sn = 0; sn < 2; ++sn)
#pragma unroll
      for (int qm = 0; qm < 2; ++qm)
        sacc[sn][qm] = (floatx4){0.f, 0.f, 0.f, 0.f};
    __builtin_amdgcn_s_setprio(1);
#pragma unroll
    for (int sn = 0; sn < 2; ++sn)
#pragma unroll
      for (int qm = 0; qm < 2; ++qm)
#pragma unroll
        for (int ks = 0; ks < 2; ++ks)
          sacc[sn][qm] = __builtin_amdgcn_mfma_f32_16x16x32_bf16(bfr[sn][ks], af[qm][ks], sacc[sn][qm], 0, 0, 0);
    __builtin_amdgcn_s_setprio(0);

    // ---- scale + mask via packed bits (word uniform per wave+tile -> LDS broadcast) ----
    const unsigned mword = mw[it * 2 + wc];
#pragma unroll
    for (int sn = 0; sn < 2; ++sn) {
      const unsigned nib = (mword >> (sn * 16)) >> (hi * 4);
#pragma unroll
      for (int j = 0; j < 4; ++j) {
        const bool mk = (nib >> j) & 1u;
#pragma unroll
        for (int qm = 0; qm < 2; ++qm)
          sacc[sn][qm][j] = mk ? -3.0e38f : sacc[sn][qm][j] * 0.125f;
      }
    }

    // ---- lane-local online softmax (q = qm*16+lo for all 8 values) ----
    float al[2];
#pragma unroll
    for (int qm = 0; qm < 2; ++qm) {
      float mx = fmaxf(fmaxf(fmaxf(sacc[0][qm][0], sacc[0][qm][1]), fmaxf(sacc[0][qm][2], sacc[0][qm][3])),
                       fmaxf(fmaxf(sacc[1][qm][0], sacc[1][qm][1]), fmaxf(sacc[1][qm][2], sacc[1][qm][3])));
      mx = fmaxf(mx, __shfl_xor(mx, 16));
      mx = fmaxf(mx, __shfl_xor(mx, 32));
      const float mn = fmaxf(m_run[qm], mx);
      al[qm] = __expf(m_run[qm] - mn);
      m_run[qm] = mn;
      l_run[qm] *= al[qm];
    }
#pragma unroll
    for (int dn = 0; dn < 4; ++dn)
#pragma unroll
      for (int qm = 0; qm < 2; ++qm)
#pragma unroll
        for (int j = 0; j < 4; ++j)
          accO[dn][qm][j] *= al[qm];

    // ---- exp, sum, pack, b64-write P to own slab ----
#pragma unroll
    for (int qm = 0; qm < 2; ++qm) {
      float s = 0.f;
      unsigned pw[2][2];
#pragma unroll
      for (int sn = 0; sn < 2; ++sn) {
        const float e0 = __expf(sacc[sn][qm][0] - m_run[qm]);
        const float e1 = __expf(sacc[sn][qm][1] - m_run[qm]);
        const float e2 = __expf(sacc[sn][qm][2] - m_run[qm]);
        const float e3 = __expf(sacc[sn][qm][3] - m_run[qm]);
        s += (e0 + e1) + (e2 + e3);
        pw[sn][0] = pack_bf2(e0, e1);
        pw[sn][1] = pack_bf2(e2, e3);
      }
      s += __shfl_xor(s, 16);
      s += __shfl_xor(s, 32);
      l_run[qm] += s;
      const int ql = qm * 16 + lo;
#pragma unroll
      for (int sn = 0; sn < 2; ++sn) {
        uint2 wv; wv.x = pw[sn][0]; wv.y = pw[sn][1];
        *reinterpret_cast<uint2*>(&Ps[w][ql * 32 + (((sn * 4 + hi) ^ (lo & 7)) * 4)]) = wv;
      }
    }

    // ---- PV = mfma(V, P): accO[d][q], K = 32 (own s-half) ----
    short8 va[4];
#pragma unroll
    for (int dn = 0; dn < 4; ++dn) {
      const int d = dn * 16 + lo;
      va[dn] = *reinterpret_cast<const short8*>(
          &KVbuf[cur][1][d * 64 + (((wc * 4 + hi) ^ (d & 7)) * 8)]);
    }
    short8 pb[2];
#pragma unroll
    for (int qm = 0; qm < 2; ++qm) {
      const int ql = qm * 16 + lo;
      uint2 a = *reinterpret_cast<const uint2*>(&Ps[w][ql * 32 + (((2 * hi) ^ (lo & 7)) * 4)]);
      uint2 bq = *reinterpret_cast<const uint2*>(&Ps[w][ql * 32 + (((2 * hi + 1) ^ (lo & 7)) * 4)]);
      uint4 comb; comb.x = a.x; comb.y = a.y; comb.z = bq.x; comb.w = bq.y;
      __builtin_memcpy(&pb[qm], &comb, 16);
    }
    __builtin_amdgcn_s_setprio(1);
#pragma unroll
    for (int dn = 0; dn < 4; ++dn)
#pragma unroll
      for (int qm = 0; qm < 2; ++qm)
        accO[dn][qm] = __builtin_amdgcn_mfma_f32_16x16x32_bf16(va[dn], pb[qm], accO[dn][qm], 0, 0, 0);
    __builtin_amdgcn_s_setprio(0);

    __syncthreads();   // drains next-tile stage; protects dbuf swap
    cur ^= 1;
  }

  // ---- epilogue: merge the 2 s-halves ----
  if (hi == 0) {
#pragma unroll
    for (int qm = 0; qm < 2; ++qm) {
      const int q = wr * 32 + qm * 16 + lo;
      mlred[wc][0][q] = m_run[qm];
      mlred[wc][1][q] = l_run[qm];
    }
  }
  __syncthreads();
  float scal[2];
#pragma unroll
  for (int qm = 0; qm < 2; ++qm) {
    const int q = wr * 32 + qm * 16 + lo;
    const float ms = fmaxf(mlred[0][0][q], mlred[1][0][q]);
    scal[qm] = __expf(m_run[qm] - ms);
  }
  float* Of = (float*)KVbuf;   // [128 q][64 d] fp32, chunk-swizzled, overlays K/V bufs
  if (wc == 0) {
#pragma unroll
    for (int dn = 0; dn < 4; ++dn)
#pragma unroll
      for (int qm = 0; qm < 2; ++qm) {
        const int q = wr * 32 + qm * 16 + lo;
        float4 v;
        v.x = accO[dn][qm][0] * scal[qm]; v.y = accO[dn][qm][1] * scal[qm];
        v.z = accO[dn][qm][2] * scal[qm]; v.w = accO[dn][qm][3] * scal[qm];
        *reinterpret_cast<float4*>(&Of[q * 64 + (((dn * 4 + hi) ^ (q & 15)) * 4)]) = v;
      }
  }
  __syncthreads();
  if (wc == 1) {
#pragma unroll
    for (int dn = 0; dn < 4; ++dn)
#pragma unroll
      for (int qm = 0; qm < 2; ++qm) {
        const int q = wr * 32 + qm * 16 + lo;
        float4* pp = reinterpret_cast<float4*>(&Of[q * 64 + (((dn * 4 + hi) ^ (q & 15)) * 4)]);
        float4 v = *pp;
        v.x += accO[dn][qm][0] * scal[qm]; v.y += accO[dn][qm][1] * scal[qm];
        v.z += accO[dn][qm][2] * scal[qm]; v.w += accO[dn][qm][3] * scal[qm];
        *pp = v;
      }
  }
  __syncthreads();
  // ---- normalized store: thread t handles q = t>>2, d = (t&3)*16 .. +15 ----
  {
    const int q = t >> 2;
    const float m0 = mlred[0][0][q], m1 = mlred[1][0][q];
    const float ms = fmaxf(m0, m1);
    const float ls = mlred[0][1][q] * __expf(m0 - ms) + mlred[1][1][q] * __expf(m1 - ms);
    const float inv = 1.0f / ls;
    u16 ov[16];
#pragma unroll
    for (int c4 = 0; c4 < 4; ++c4) {
      const int c = (t & 3) * 4 + c4;
      float4 v = *reinterpret_cast<const float4*>(&Of[q * 64 + ((c ^ (q & 15)) * 4)]);
      ov[c4 * 4 + 0] = f2bf(v.x * inv); ov[c4 * 4 + 1] = f2bf(v.y * inv);
      ov[c4 * 4 + 2] = f2bf(v.z * inv); ov[c4 * 4 + 3] = f2bf(v.w * inv);
    }
    u16* dst = Og + qbase + (long)q * 512 + (t & 3) * 16;
    uint4 w0, w1;
    __builtin_memcpy(&w0, &ov[0], 16);
    __builtin_memcpy(&w1, &ov[8], 16);
    *reinterpret_cast<uint4*>(dst) = w0;
    *reinterpret_cast<uint4*>(dst + 8) = w1;
  }
}

// ---------------- residual + P-way partial sums + optional bias + layernorm ----------------
template<int P, bool WRITE_BF>
__global__ __launch_bounds__(64) void lnp_kernel(const float* __restrict__ r1,
    const float* __restrict__ parts, long pstride,
    const float* __restrict__ bias,
    const float* __restrict__ g, const float* __restrict__ be,
    float* __restrict__ xf, u16* __restrict__ xb) {
  const long base = (long)blockIdx.x * 512;
  const int t = threadIdx.x;
  float v[8]; float s = 0.f;
#pragma unroll
  for (int j = 0; j < 8; ++j) {
    int i = t + j * 64;
    float acc = r1[base + i] + (bias ? bias[i] : 0.f);
#pragma unroll
    for (int q = 0; q < P; ++q) acc += parts[q * pstride + base + i];
    v[j] = acc; s += acc;
  }
#pragma unroll
  for (int o = 32; o; o >>= 1) s += __shfl_xor(s, o);
  const float mu = s * (1.0f / 512.0f);
  float q2 = 0.f;
#pragma unroll
  for (int j = 0; j < 8; ++j) { float d = v[j] - mu; q2 += d * d; }
#pragma unroll
  for (int o = 32; o; o >>= 1) q2 += __shfl_xor(q2, o);
  const float rs = rsqrtf(q2 * (1.0f / 512.0f) + 1e-5f);
#pragma unroll
  for (int j = 0; j < 8; ++j) {
    int i = t + j * 64;
    float o = (v[j] - mu) * rs * g[i] + be[i];
    xf[base + i] = o;
    if (WRITE_BF) xb[base + i] = f2bf(o);
  }
}

// ---------------- V transpose: Vt[b][h][d][s] = KV[b*S+s][512 + h*64 + d] ----------------
__global__ __launch_bounds__(256) void transpose_v_kernel(const u16* __restrict__ KV,
                                                          u16* __restrict__ Vt) {
  __shared__ u16 tile[128 * 65];
  const int z = blockIdx.y;
  const int b = z >> 3, h = z & 7;
  const int s0 = blockIdx.x * 128;
  const int t = threadIdx.x;
#pragma unroll
  for (int k = 0; k < 32; ++k) {
    int i = k * 256 + t;
    int s = i >> 6, d = i & 63;
    tile[s * 65 + d] = KV[(long)(b * 2048 + s0 + s) * 1024 + 512 + h * 64 + d];
  }
  __syncthreads();
#pragma unroll
  for (int k = 0; k < 32; ++k) {
    int i = k * 256 + t;
    int d = i >> 7, sl = i & 127;
    Vt[((long)z * 64 + d) * 2048 + s0 + sl] = tile[sl * 65 + d];
  }
}

extern "C" void kernel_launch(void* const* d_in, const int* in_sizes, int n_in,
                              void* d_out, int out_size, void* d_ws, size_t ws_size,
                              hipStream_t stream) {
  const float* tgt    = (const float*)d_in[0];
  const float* memory = (const float*)d_in[1];
  const void*  maskraw= (const void*)d_in[2];
  const float* Wq  = (const float*)d_in[3];
  const float* Wkv = (const float*)d_in[4];
  const float* Wo  = (const float*)d_in[5];
  const float* W1  = (const float*)d_in[6];
  const float* b1  = (const float*)d_in[7];
  const float* W2  = (const float*)d_in[8];
  const float* b2  = (const float*)d_in[9];
  const float* g1  = (const float*)d_in[10];
  const float* be1 = (const float*)d_in[11];
  const float* g2  = (const float*)d_in[12];
  const float* be2 = (const float*)d_in[13];

  constexpr int B = 4, V = 1024, S = 2048, D = 512, H = 8, FF = 2048, hd = 64;
  const long BVD = (long)B * V * D;

  char* p = (char*)d_ws;
  auto alloc = [&](size_t bytes) -> void* {
    void* r = (void*)p; p += (bytes + 255) & ~(size_t)255; return r;
  };
  u16*  tgt_b = (u16*)alloc((size_t)B * V * D * 2);
  u16*  mem_b = (u16*)alloc((size_t)B * S * D * 2);
  u16*  wq_b  = (u16*)alloc((size_t)D * D * 2);
  u16*  wkv_b = (u16*)alloc((size_t)2 * D * D * 2);
  u16*  wo_b  = (u16*)alloc((size_t)D * D * 2);
  u16*  w1_b  = (u16*)alloc((size_t)FF * D * 2);
  u16*  w2_b  = (u16*)alloc((size_t)D * FF * 2);
  u16*  Qb    = (u16*)alloc((size_t)B * V * D * 2);
  u16*  KVb   = (u16*)alloc((size_t)B * S * 2 * D * 2);
  u16*  Vt    = (u16*)alloc((size_t)B * H * hd * S * 2);
  u16*  attn_b= (u16*)alloc((size_t)B * V * D * 2);
  float* projP = (float*)alloc((size_t)4 * BVD * 4);
  float* xf   = (float*)alloc((size_t)BVD * 4);
  u16*  xb    = (u16*)alloc((size_t)BVD * 2);
  u16*  hb    = (u16*)alloc((size_t)B * V * FF * 2);
  float* ffbP = (float*)alloc((size_t)4 * BVD * 4);
  unsigned* mbitsW = (unsigned*)alloc((size_t)(B * S / 32) * 4);

  auto cast = [&](const float* src, u16* dst, long n) {
    int n4 = (int)(n / 4);
    int grid = (n4 + 255) / 256; if (grid > 2048) grid = 2048; if (grid < 1) grid = 1;
    cast_bf16_kernel<<<dim3(grid), dim3(256), 0, stream>>>(src, dst, n4);
  };
  cast(tgt, tgt_b, (long)B * V * D);
  cast(memory, mem_b, (long)B * S * D);
  cast(Wq, wq_b, (long)D * D);
  cast(Wkv, wkv_b, (long)2 * D * D);
  cast(Wo, wo_b, (long)D * D);
  cast(W1, w1_b, (long)FF * D);
  cast(W2, w2_b, (long)D * FF);

  mask_bits_kernel<<<dim3(1), 256, 0, stream>>>(maskraw, mbitsW, B * S);

  // Q = tgt @ Wq^T
  gemm_bt<0><<<dim3(D / 128, (B * V) / 128, 1), 256, 0, stream>>>(
      tgt_b, wq_b, Qb, nullptr, B * V, D, D, D, D, D, 0, 0, 0);
  // KV = memory @ Wkv^T
  gemm_bt<0><<<dim3((2 * D) / 128, (B * S) / 128, 1), 256, 0, stream>>>(
      mem_b, wkv_b, KVb, nullptr, B * S, 2 * D, D, D, D, 2 * D, 0, 0, 0);
  // Vt[b][h][d][s]
  transpose_v_kernel<<<dim3(S / 128, B * H), 256, 0, stream>>>(KVb, Vt);

  // fused flash attention -> attn_b (bf16)
  flash_attn_kernel<<<dim3(8, B * H), 512, 0, stream>>>(
      Qb, KVb, Vt, mbitsW, attn_b);

  // proj quarters = attn @ Wo^T, split-K z=4
  gemm_bt<1><<<dim3(D / 128, (B * V) / 128, 4), 256, 0, stream>>>(
      attn_b, wo_b, projP, nullptr, B * V, D, D / 4, D, D, D,
      (long)(D / 4), (long)(D / 4), BVD);
  // x = LN(tgt + sum proj quarters)
  lnp_kernel<4, true><<<dim3(B * V), 64, 0, stream>>>(
      tgt, projP, BVD, nullptr, g1, be1, xf, xb);
  // h = relu(x @ W1^T + b1)
  gemm_bt<2><<<dim3(FF / 128, (B * V) / 128, 1), 256, 0, stream>>>(
      xb, w1_b, hb, b1, B * V, FF, D, D, D, FF, 0, 0, 0);
  // ff quarters = h @ W2^T, split-K z=4 (b2 added in LN2)
  gemm_bt<1><<<dim3(D / 128, (B * V) / 128, 4), 256, 0, stream>>>(
      hb, w2_b, ffbP, nullptr, B * V, D, FF / 4, FF, FF, D,
      (long)(FF / 4), (long)(FF / 4), BVD);
  // out = LN(x + sum ff quarters + b2) -> fp32 d_out
  lnp_kernel<4, false><<<dim3(B * V), 64, 0, stream>>>(
      xf, ffbP, BVD, b2, g2, be2, (float*)d_out, nullptr);
}

// Round 7
// 268.451 us; speedup vs baseline: 2.3784x; 1.1280x over previous
//
#include <hip/hip_runtime.h>

typedef unsigned short u16;
typedef __attribute__((ext_vector_type(8))) short short8;
typedef __attribute__((ext_vector_type(4))) float floatx4;

#define AS1 __attribute__((address_space(1)))
#define AS3 __attribute__((address_space(3)))

__device__ __forceinline__ u16 f2bf(float f) {
  unsigned u = __float_as_uint(f);
  u = u + 0x7FFFu + ((u >> 16) & 1u);   // RNE
  return (u16)(u >> 16);
}
__device__ __forceinline__ unsigned pack_bf2(float a, float b) {
  return (unsigned)f2bf(a) | ((unsigned)f2bf(b) << 16);
}

// ---------------- fused fp32 -> bf16 cast of all 7 tensors, one launch ----------------
// segment boundaries in float4 units (hardcoded for this problem's sizes)
__global__ __launch_bounds__(256) void cast_all_kernel(
    const float* __restrict__ s0, u16* __restrict__ d0,   // tgt    524288
    const float* __restrict__ s1, u16* __restrict__ d1,   // mem   1048576
    const float* __restrict__ s2, u16* __restrict__ d2,   // wq      65536
    const float* __restrict__ s3, u16* __restrict__ d3,   // wkv    131072
    const float* __restrict__ s4, u16* __restrict__ d4,   // wo      65536
    const float* __restrict__ s5, u16* __restrict__ d5,   // w1     262144
    const float* __restrict__ s6, u16* __restrict__ d6)   // w2     262144
{
  const int total = 2359296;
  int i = blockIdx.x * 256 + threadIdx.x;
  const int stride = gridDim.x * 256;
  for (; i < total; i += stride) {
    const float* s; u16* d; int loc;
    if (i < 524288)        { s = s0; d = d0; loc = i; }
    else if (i < 1572864)  { s = s1; d = d1; loc = i - 524288; }
    else if (i < 1638400)  { s = s2; d = d2; loc = i - 1572864; }
    else if (i < 1769472)  { s = s3; d = d3; loc = i - 1638400; }
    else if (i < 1835008)  { s = s4; d = d4; loc = i - 1769472; }
    else if (i < 2097152)  { s = s5; d = d5; loc = i - 1835008; }
    else                   { s = s6; d = d6; loc = i - 2097152; }
    float4 v = reinterpret_cast<const float4*>(s)[loc];
    ushort4 o;
    o.x = f2bf(v.x); o.y = f2bf(v.y); o.z = f2bf(v.z); o.w = f2bf(v.w);
    reinterpret_cast<ushort4*>(d)[loc] = o;
  }
}

// ---------------- mask -> packed bits (bool-bytes / int32 / float32), vectorized ----------------
__global__ __launch_bounds__(256) void mask_bits_kernel(const void* __restrict__ mraw,
                                                        unsigned* __restrict__ mout, int n) {
  __shared__ int mode;
  const int t = threadIdx.x;
  const int* mi = (const int*)mraw;
  if (t == 0) mode = 0;
  __syncthreads();
  int local = 0;
  for (int i = t; i < 2048; i += 256) {
    unsigned v = (unsigned)mi[i];
    if (v == 0x3F800000u) { local = 2; break; }
    if (v > 1u) local = 1;
  }
  atomicMax(&mode, local);
  __syncthreads();
  const int m = mode;
  const uint4* m4 = (const uint4*)mraw;
  const int nw = n / 32;                 // 256 words
  for (int wk = t; wk < nw; wk += 256) {
    unsigned bits = 0;
    if (m == 1) {                        // 1-byte bools: 32 bytes = 2 x uint4
      uint4 a = m4[wk * 2], b = m4[wk * 2 + 1];
      unsigned ww[8] = {a.x, a.y, a.z, a.w, b.x, b.y, b.z, b.w};
#pragma unroll
      for (int k = 0; k < 8; ++k)
#pragma unroll
        for (int j = 0; j < 4; ++j)
          bits |= (((ww[k] >> (j * 8)) & 0xFFu) ? 1u : 0u) << (k * 4 + j);
    } else {                             // 32 dwords = 8 x uint4
#pragma unroll
      for (int k = 0; k < 8; ++k) {
        uint4 a = m4[wk * 8 + k];
        unsigned t0 = (m == 2) ? ((a.x << 1) ? 1u : 0u) : (a.x ? 1u : 0u);
        unsigned t1 = (m == 2) ? ((a.y << 1) ? 1u : 0u) : (a.y ? 1u : 0u);
        unsigned t2 = (m == 2) ? ((a.z << 1) ? 1u : 0u) : (a.z ? 1u : 0u);
        unsigned t3 = (m == 2) ? ((a.w << 1) ? 1u : 0u) : (a.w ? 1u : 0u);
        bits |= (t0 | (t1 << 1) | (t2 << 2) | (t3 << 3)) << (k * 4);
      }
    }
    mout[wk] = bits;
  }
}

// ---------------- generic C = epilogue(A @ B^T), bf16, double-buffered 2-phase ----------------
// REQUIRES: M, N multiples of 128; K multiple of 32 (all call sites satisfy this).
// EPI: 0 = bf16, 1 = fp32, 2 = bias+relu -> bf16, 3 = bias -> fp32, 4 = *0.125 -> bf16
template<int EPI>
__global__ __launch_bounds__(256) void gemm_bt(
    const u16* __restrict__ A, const u16* __restrict__ B, void* __restrict__ Cv,
    const float* __restrict__ bias,
    int M, int N, int K, int lda, int ldb, int ldc,
    long aBatch, long bBatch, long cBatch)
{
  __shared__ u16 As[2][128 * 32];
  __shared__ u16 Bs[2][128 * 32];
  const int t = threadIdx.x;
  const int l = t & 63;
  const int w = t >> 6;
  const int wr = w >> 1, wc = w & 1;
  const int m0 = blockIdx.y * 128, n0 = blockIdx.x * 128;
  const long z = blockIdx.z;
  const u16* Ab = A + z * aBatch;
  const u16* Bb = B + z * bBatch;

  floatx4 acc[4][4];
#pragma unroll
  for (int m = 0; m < 4; ++m)
#pragma unroll
    for (int n = 0; n < 4; ++n)
      acc[m][n] = (floatx4){0.f, 0.f, 0.f, 0.f};

  const int row_st = t >> 2;
  const int kcol = (t & 3) * 8;

  auto stage = [&](int buf, int kt) {
#pragma unroll
    for (int c = 0; c < 2; ++c) {
      const int rA = m0 + c * 64 + row_st;
      const int rB = n0 + c * 64 + row_st;
      const int li = (c * 256 + t) * 8;
      __builtin_amdgcn_global_load_lds(
          (const AS1 void*)(Ab + (long)rA * lda + kt + kcol),
          (AS3 void*)(As[buf] + li), 16, 0, 0);
      __builtin_amdgcn_global_load_lds(
          (const AS1 void*)(Bb + (long)rB * ldb + kt + kcol),
          (AS3 void*)(Bs[buf] + li), 16, 0, 0);
    }
  };

  stage(0, 0);
  __syncthreads();
  int cur = 0;
  for (int kt = 0; kt < K; kt += 32) {
    if (kt + 32 < K) stage(cur ^ 1, kt + 32);

    short8 af[4], bf[4];
#pragma unroll
    for (int m = 0; m < 4; ++m)
      af[m] = *reinterpret_cast<const short8*>(&As[cur][(wr * 64 + m * 16 + (l & 15)) * 32 + (l >> 4) * 8]);
#pragma unroll
    for (int n = 0; n < 4; ++n)
      bf[n] = *reinterpret_cast<const short8*>(&Bs[cur][(wc * 64 + n * 16 + (l & 15)) * 32 + (l >> 4) * 8]);

    __builtin_amdgcn_s_setprio(1);
#pragma unroll
    for (int m = 0; m < 4; ++m)
#pragma unroll
      for (int n = 0; n < 4; ++n)
        acc[m][n] = __builtin_amdgcn_mfma_f32_16x16x32_bf16(af[m], bf[n], acc[m][n], 0, 0, 0);
    __builtin_amdgcn_s_setprio(0);

    __syncthreads();
    cur ^= 1;
  }

  const int cr = (l >> 4) * 4;
  const int cc = l & 15;
#pragma unroll
  for (int m = 0; m < 4; ++m) {
#pragma unroll
    for (int j = 0; j < 4; ++j) {
      const int row = m0 + wr * 64 + m * 16 + cr + j;
#pragma unroll
      for (int n = 0; n < 4; ++n) {
        const int col = n0 + wc * 64 + n * 16 + cc;
        float v = acc[m][n][j];
        long idx = z * cBatch + (long)row * ldc + col;
        if constexpr (EPI == 0) {
          ((u16*)Cv)[idx] = f2bf(v);
        } else if constexpr (EPI == 1) {
          ((float*)Cv)[idx] = v;
        } else if constexpr (EPI == 2) {
          v += bias[col]; v = fmaxf(v, 0.f);
          ((u16*)Cv)[idx] = f2bf(v);
        } else if constexpr (EPI == 3) {
          v += bias[col];
          ((float*)Cv)[idx] = v;
        } else {
          ((u16*)Cv)[idx] = f2bf(v * 0.125f);
        }
      }
    }
  }
}

// ---------------- fused flash cross-attention v4 ----------------
// grid (16, 32) XCD-remapped => 512 blocks = 2/CU. Block 512 = 8 waves =
// 4 q-quarters (16 rows each) x 2 s-halves. S-tile 64, K/V dbuf, 1 barrier/tile.
// St = mfma(K,Q) -> col=q=lo (lane-local softmax); PV = mfma(V,P) -> col=q=lo.
// Q pre-scaled by 0.125 in its GEMM epilogue.
__global__ __launch_bounds__(512, 4) void flash_attn_kernel(
    const u16* __restrict__ Qg, const u16* __restrict__ KVg,
    const u16* __restrict__ Vtg, const unsigned* __restrict__ mbits,
    u16* __restrict__ Og)
{
  __shared__ __align__(16) u16 KVbuf[2][2][64 * 64];  // 32 KB
  __shared__ __align__(16) u16 Ps[8][16 * 32];        // 8 KB (per-wave P slab)
  __shared__ float mlred[2][2][64];                   // 1 KB
  __shared__ unsigned mw[64];

  const int t = threadIdx.x;
  const int l = t & 63;
  const int w = t >> 6;        // 0..7
  const int wr = w >> 1;       // 0..3 : q quarter (16 rows)
  const int wc = w & 1;        // 0..1 : s half (32 cols)
  const int lo = l & 15, hi = l >> 4;

  // XCD-bijective remap: 512 blocks, xcd k gets vid [64k, 64k+64) -> bh in [4k,4k+4)
  const int id = blockIdx.y * 16 + blockIdx.x;
  const int vid = (id & 7) * 64 + (id >> 3);
  const int qt = vid & 15, bh = vid >> 4;
  const int b = bh >> 3, h = bh & 7;

  const long qbase = ((long)b * 1024 + qt * 64) * 512 + h * 64;
  const long kbase = ((long)b * 2048) * 1024 + h * 64;
  const long vbase = ((long)bh * 64) * 2048;

  if (t < 64) mw[t] = mbits[b * 64 + t];

  auto stage_kv = [&](int buf, int soff) {
    const int s = t >> 3, c = t & 7;
    __builtin_amdgcn_global_load_lds(
        (const AS1 void*)(KVg + kbase + (long)(soff + s) * 1024 + ((c ^ (s & 7)) * 8)),
        (AS3 void*)(&KVbuf[buf][0][t * 8]), 16, 0, 0);
    __builtin_amdgcn_global_load_lds(
        (const AS1 void*)(Vtg + vbase + (long)s * 2048 + soff + ((c ^ (s & 7)) * 8)),
        (AS3 void*)(&KVbuf[buf][1][t * 8]), 16, 0, 0);
  };

  stage_kv(0, 0);

  // Q fragments (pre-scaled by 0.125): global -> registers, once
  short8 af[2];   // [ks]; B-frag: row=q=lo, k = ks*32 + hi*8 + j
#pragma unroll
  for (int ks = 0; ks < 2; ++ks)
    af[ks] = *reinterpret_cast<const short8*>(
        Qg + qbase + (long)(wr * 16 + lo) * 512 + ks * 32 + hi * 8);

  __syncthreads();

  floatx4 accO[4];   // [dn]: row d = dn*16+hi*4+j, col q = lo
#pragma unroll
  for (int dn = 0; dn < 4; ++dn)
    accO[dn] = (floatx4){0.f, 0.f, 0.f, 0.f};
  float m_run = -1.0e30f, l_run = 0.f;

  int cur = 0;
  for (int it = 0; it < 32; ++it) {
    const int s0 = it * 64;
    if (it + 1 < 32) stage_kv(cur ^ 1, s0 + 64);

    // ---- St = mfma(K, Q): per wave 32s x 16q ----
    short8 bfr[2][2];
#pragma unroll
    for (int sn = 0; sn < 2; ++sn)
#pragma unroll
      for (int ks = 0; ks < 2; ++ks) {
        const int srow = wc * 32 + sn * 16 + lo;
        bfr[sn][ks] = *reinterpret_cast<const short8*>(
            &KVbuf[cur][0][srow * 64 + (((ks * 4 + hi) ^ (lo & 7)) * 8)]);
      }
    floatx4 sacc[2];
#pragma unroll
    for (int sn = 0; sn < 2; ++sn)
      sacc[sn] = (floatx4){0.f, 0.f, 0.f, 0.f};
    __builtin_amdgcn_s_setprio(1);
#pragma unroll
    for (int sn = 0; sn < 2; ++sn)
#pragma unroll
      for (int ks = 0; ks < 2; ++ks)
        sacc[sn] = __builtin_amdgcn_mfma_f32_16x16x32_bf16(bfr[sn][ks], af[ks], sacc[sn], 0, 0, 0);
    __builtin_amdgcn_s_setprio(0);

    // ---- mask (Q pre-scaled; sentinel only) ----
    const unsigned mword = mw[it * 2 + wc];
#pragma unroll
    for (int sn = 0; sn < 2; ++sn) {
      const unsigned nib = (mword >> (sn * 16)) >> (hi * 4);
#pragma unroll
      for (int j = 0; j < 4; ++j)
        if ((nib >> j) & 1u) sacc[sn][j] = -3.0e38f;
    }

    // ---- lane-local online softmax (q = lo) ----
    float mx = fmaxf(fmaxf(fmaxf(sacc[0][0], sacc[0][1]), fmaxf(sacc[0][2], sacc[0][3])),
                     fmaxf(fmaxf(sacc[1][0], sacc[1][1]), fmaxf(sacc[1][2], sacc[1][3])));
    mx = fmaxf(mx, __shfl_xor(mx, 16));
    mx = fmaxf(mx, __shfl_xor(mx, 32));
    const float mn = fmaxf(m_run, mx);
    const float al = __expf(m_run - mn);
    m_run = mn;
    l_run *= al;
#pragma unroll
    for (int dn = 0; dn < 4; ++dn)
#pragma unroll
      for (int j = 0; j < 4; ++j)
        accO[dn][j] *= al;

    // ---- exp, sum, pack, b64-write P to own slab ----
    {
      float s = 0.f;
      unsigned pw[2][2];
#pragma unroll
      for (int sn = 0; sn < 2; ++sn) {
        const float e0 = __expf(sacc[sn][0] - m_run);
        const float e1 = __expf(sacc[sn][1] - m_run);
        const float e2 = __expf(sacc[sn][2] - m_run);
        const float e3 = __expf(sacc[sn][3] - m_run);
        s += (e0 + e1) + (e2 + e3);
        pw[sn][0] = pack_bf2(e0, e1);
        pw[sn][1] = pack_bf2(e2, e3);
      }
      s += __shfl_xor(s, 16);
      s += __shfl_xor(s, 32);
      l_run += s;
#pragma unroll
      for (int sn = 0; sn < 2; ++sn) {
        uint2 wv; wv.x = pw[sn][0]; wv.y = pw[sn][1];
        *reinterpret_cast<uint2*>(&Ps[w][lo * 32 + (((sn * 4 + hi) ^ (lo & 7)) * 4)]) = wv;
      }
    }

    // ---- PV = mfma(V, P): accO[d][q], K = 32 (own s-half) ----
    short8 va[4];
#pragma unroll
    for (int dn = 0; dn < 4; ++dn) {
      const int d = dn * 16 + lo;
      va[dn] = *reinterpret_cast<const short8*>(
          &KVbuf[cur][1][d * 64 + (((wc * 4 + hi) ^ (d & 7)) * 8)]);
    }
    short8 pb;
    {
      uint2 a = *reinterpret_cast<const uint2*>(&Ps[w][lo * 32 + (((2 * hi) ^ (lo & 7)) * 4)]);
      uint2 bq = *reinterpret_cast<const uint2*>(&Ps[w][lo * 32 + (((2 * hi + 1) ^ (lo & 7)) * 4)]);
      uint4 comb; comb.x = a.x; comb.y = a.y; comb.z = bq.x; comb.w = bq.y;
      __builtin_memcpy(&pb, &comb, 16);
    }
    __builtin_amdgcn_s_setprio(1);
#pragma unroll
    for (int dn = 0; dn < 4; ++dn)
      accO[dn] = __builtin_amdgcn_mfma_f32_16x16x32_bf16(va[dn], pb, accO[dn], 0, 0, 0);
    __builtin_amdgcn_s_setprio(0);

    __syncthreads();
    cur ^= 1;
  }

  // ---- epilogue: merge the 2 s-halves ----
  if (hi == 0) {
    const int q = wr * 16 + lo;
    mlred[wc][0][q] = m_run;
    mlred[wc][1][q] = l_run;
  }
  __syncthreads();
  float scal;
  {
    const int q = wr * 16 + lo;
    const float ms = fmaxf(mlred[0][0][q], mlred[1][0][q]);
    scal = __expf(m_run - ms);
  }
  float* Of = (float*)KVbuf;   // [64 q][64 d] fp32, chunk-swizzled
  if (wc == 0) {
#pragma unroll
    for (int dn = 0; dn < 4; ++dn) {
      const int q = wr * 16 + lo;
      float4 v;
      v.x = accO[dn][0] * scal; v.y = accO[dn][1] * scal;
      v.z = accO[dn][2] * scal; v.w = accO[dn][3] * scal;
      *reinterpret_cast<float4*>(&Of[q * 64 + (((dn * 4 + hi) ^ (q & 15)) * 4)]) = v;
    }
  }
  __syncthreads();
  if (wc == 1) {
#pragma unroll
    for (int dn = 0; dn < 4; ++dn) {
      const int q = wr * 16 + lo;
      float4* pp = reinterpret_cast<float4*>(&Of[q * 64 + (((dn * 4 + hi) ^ (q & 15)) * 4)]);
      float4 v = *pp;
      v.x += accO[dn][0] * scal; v.y += accO[dn][1] * scal;
      v.z += accO[dn][2] * scal; v.w += accO[dn][3] * scal;
      *pp = v;
    }
  }
  __syncthreads();
  // ---- normalized store: thread t -> q = t>>3, d = (t&7)*8 .. +7 ----
  {
    const int q = t >> 3;
    const int dc = t & 7;
    const float m0 = mlred[0][0][q], m1 = mlred[1][0][q];
    const float ms = fmaxf(m0, m1);
    const float ls = mlred[0][1][q] * __expf(m0 - ms) + mlred[1][1][q] * __expf(m1 - ms);
    const float inv = 1.0f / ls;
    float4 v0 = *reinterpret_cast<const float4*>(&Of[q * 64 + (((dc * 2) ^ (q & 15)) * 4)]);
    float4 v1 = *reinterpret_cast<const float4*>(&Of[q * 64 + (((dc * 2 + 1) ^ (q & 15)) * 4)]);
    u16 ov[8];
    ov[0] = f2bf(v0.x * inv); ov[1] = f2bf(v0.y * inv);
    ov[2] = f2bf(v0.z * inv); ov[3] = f2bf(v0.w * inv);
    ov[4] = f2bf(v1.x * inv); ov[5] = f2bf(v1.y * inv);
    ov[6] = f2bf(v1.z * inv); ov[7] = f2bf(v1.w * inv);
    uint4 wv;
    __builtin_memcpy(&wv, ov, 16);
    *reinterpret_cast<uint4*>(Og + qbase + (long)q * 512 + dc * 8) = wv;
  }
}

// ---------------- residual + P-way partial sums + optional bias + layernorm ----------------
template<int P, bool WRITE_BF>
__global__ __launch_bounds__(64) void lnp_kernel(const float* __restrict__ r1,
    const float* __restrict__ parts, long pstride,
    const float* __restrict__ bias,
    const float* __restrict__ g, const float* __restrict__ be,
    float* __restrict__ xf, u16* __restrict__ xb) {
  const long base = (long)blockIdx.x * 512;
  const int t = threadIdx.x;
  float v[8]; float s = 0.f;
#pragma unroll
  for (int j = 0; j < 8; ++j) {
    int i = t + j * 64;
    float acc = r1[base + i] + (bias ? bias[i] : 0.f);
#pragma unroll
    for (int q = 0; q < P; ++q) acc += parts[q * pstride + base + i];
    v[j] = acc; s += acc;
  }
#pragma unroll
  for (int o = 32; o; o >>= 1) s += __shfl_xor(s, o);
  const float mu = s * (1.0f / 512.0f);
  float q2 = 0.f;
#pragma unroll
  for (int j = 0; j < 8; ++j) { float d = v[j] - mu; q2 += d * d; }
#pragma unroll
  for (int o = 32; o; o >>= 1) q2 += __shfl_xor(q2, o);
  const float rs = rsqrtf(q2 * (1.0f / 512.0f) + 1e-5f);
#pragma unroll
  for (int j = 0; j < 8; ++j) {
    int i = t + j * 64;
    float o = (v[j] - mu) * rs * g[i] + be[i];
    xf[base + i] = o;
    if (WRITE_BF) xb[base + i] = f2bf(o);
  }
}

// ---------------- V transpose: Vt[b][h][d][s] = KV[b*S+s][512 + h*64 + d] ----------------
__global__ __launch_bounds__(256) void transpose_v_kernel(const u16* __restrict__ KV,
                                                          u16* __restrict__ Vt) {
  __shared__ u16 tile[128 * 65];
  const int z = blockIdx.y;
  const int b = z >> 3, h = z & 7;
  const int s0 = blockIdx.x * 128;
  const int t = threadIdx.x;
#pragma unroll
  for (int k = 0; k < 32; ++k) {
    int i = k * 256 + t;
    int s = i >> 6, d = i & 63;
    tile[s * 65 + d] = KV[(long)(b * 2048 + s0 + s) * 1024 + 512 + h * 64 + d];
  }
  __syncthreads();
#pragma unroll
  for (int k = 0; k < 32; ++k) {
    int i = k * 256 + t;
    int d = i >> 7, sl = i & 127;
    Vt[((long)z * 64 + d) * 2048 + s0 + sl] = tile[sl * 65 + d];
  }
}

extern "C" void kernel_launch(void* const* d_in, const int* in_sizes, int n_in,
                              void* d_out, int out_size, void* d_ws, size_t ws_size,
                              hipStream_t stream) {
  const float* tgt    = (const float*)d_in[0];
  const float* memory = (const float*)d_in[1];
  const void*  maskraw= (const void*)d_in[2];
  const float* Wq  = (const float*)d_in[3];
  const float* Wkv = (const float*)d_in[4];
  const float* Wo  = (const float*)d_in[5];
  const float* W1  = (const float*)d_in[6];
  const float* b1  = (const float*)d_in[7];
  const float* W2  = (const float*)d_in[8];
  const float* b2  = (const float*)d_in[9];
  const float* g1  = (const float*)d_in[10];
  const float* be1 = (const float*)d_in[11];
  const float* g2  = (const float*)d_in[12];
  const float* be2 = (const float*)d_in[13];

  constexpr int B = 4, V = 1024, S = 2048, D = 512, H = 8, FF = 2048, hd = 64;
  const long BVD = (long)B * V * D;

  char* p = (char*)d_ws;
  auto alloc = [&](size_t bytes) -> void* {
    void* r = (void*)p; p += (bytes + 255) & ~(size_t)255; return r;
  };
  u16*  tgt_b = (u16*)alloc((size_t)B * V * D * 2);
  u16*  mem_b = (u16*)alloc((size_t)B * S * D * 2);
  u16*  wq_b  = (u16*)alloc((size_t)D * D * 2);
  u16*  wkv_b = (u16*)alloc((size_t)2 * D * D * 2);
  u16*  wo_b  = (u16*)alloc((size_t)D * D * 2);
  u16*  w1_b  = (u16*)alloc((size_t)FF * D * 2);
  u16*  w2_b  = (u16*)alloc((size_t)D * FF * 2);
  u16*  Qb    = (u16*)alloc((size_t)B * V * D * 2);
  u16*  KVb   = (u16*)alloc((size_t)B * S * 2 * D * 2);
  u16*  Vt    = (u16*)alloc((size_t)B * H * hd * S * 2);
  u16*  attn_b= (u16*)alloc((size_t)B * V * D * 2);
  float* projP = (float*)alloc((size_t)4 * BVD * 4);
  float* xf   = (float*)alloc((size_t)BVD * 4);
  u16*  xb    = (u16*)alloc((size_t)BVD * 2);
  u16*  hb    = (u16*)alloc((size_t)B * V * FF * 2);
  float* ffbP = (float*)alloc((size_t)4 * BVD * 4);
  unsigned* mbitsW = (unsigned*)alloc((size_t)(B * S / 32) * 4);

  // one fused cast launch for all 7 tensors
  cast_all_kernel<<<dim3(2048), 256, 0, stream>>>(
      tgt, tgt_b, memory, mem_b, Wq, wq_b, Wkv, wkv_b, Wo, wo_b, W1, w1_b, W2, w2_b);

  mask_bits_kernel<<<dim3(1), 256, 0, stream>>>(maskraw, mbitsW, B * S);

  // Q = (tgt @ Wq^T) * 0.125  (scale folded into epilogue)
  gemm_bt<4><<<dim3(D / 128, (B * V) / 128, 1), 256, 0, stream>>>(
      tgt_b, wq_b, Qb, nullptr, B * V, D, D, D, D, D, 0, 0, 0);
  // KV = memory @ Wkv^T
  gemm_bt<0><<<dim3((2 * D) / 128, (B * S) / 128, 1), 256, 0, stream>>>(
      mem_b, wkv_b, KVb, nullptr, B * S, 2 * D, D, D, D, 2 * D, 0, 0, 0);
  // Vt[b][h][d][s]
  transpose_v_kernel<<<dim3(S / 128, B * H), 256, 0, stream>>>(KVb, Vt);

  // fused flash attention -> attn_b (bf16)
  flash_attn_kernel<<<dim3(16, B * H), 512, 0, stream>>>(
      Qb, KVb, Vt, mbitsW, attn_b);

  // proj quarters = attn @ Wo^T, split-K z=4
  gemm_bt<1><<<dim3(D / 128, (B * V) / 128, 4), 256, 0, stream>>>(
      attn_b, wo_b, projP, nullptr, B * V, D, D / 4, D, D, D,
      (long)(D / 4), (long)(D / 4), BVD);
  // x = LN(tgt + sum proj quarters)
  lnp_kernel<4, true><<<dim3(B * V), 64, 0, stream>>>(
      tgt, projP, BVD, nullptr, g1, be1, xf, xb);
  // h = relu(x @ W1^T + b1)
  gemm_bt<2><<<dim3(FF / 128, (B * V) / 128, 1), 256, 0, stream>>>(
      xb, w1_b, hb, b1, B * V, FF, D, D, D, FF, 0, 0, 0);
  // ff quarters = h @ W2^T, split-K z=4 (b2 added in LN2)
  gemm_bt<1><<<dim3(D / 128, (B * V) / 128, 4), 256, 0, stream>>>(
      hb, w2_b, ffbP, nullptr, B * V, D, FF / 4, FF, FF, D,
      (long)(FF / 4), (long)(FF / 4), BVD);
  // out = LN(x + sum ff quarters + b2) -> fp32 d_out
  lnp_kernel<4, false><<<dim3(B * V), 64, 0, stream>>>(
      xf, ffbP, BVD, b2, g2, be2, (float*)d_out, nullptr);
}

// Round 9
// 262.765 us; speedup vs baseline: 2.4299x; 1.0216x over previous
//
#include <hip/hip_runtime.h>

typedef unsigned short u16;
typedef __attribute__((ext_vector_type(8))) short short8;
typedef __attribute__((ext_vector_type(4))) float floatx4;

#define AS1 __attribute__((address_space(1)))
#define AS3 __attribute__((address_space(3)))

__device__ __forceinline__ u16 f2bf(float f) {
  unsigned u = __float_as_uint(f);
  u = u + 0x7FFFu + ((u >> 16) & 1u);   // RNE
  return (u16)(u >> 16);
}
__device__ __forceinline__ unsigned pack_bf2(float a, float b) {
  return (unsigned)f2bf(a) | ((unsigned)f2bf(b) << 16);
}

// ---------------- fused fp32 -> bf16 cast of all 7 tensors, one launch ----------------
__global__ __launch_bounds__(256) void cast_all_kernel(
    const float* __restrict__ s0, u16* __restrict__ d0,   // tgt    524288 f4
    const float* __restrict__ s1, u16* __restrict__ d1,   // mem   1048576
    const float* __restrict__ s2, u16* __restrict__ d2,   // wq      65536
    const float* __restrict__ s3, u16* __restrict__ d3,   // wkv    131072
    const float* __restrict__ s4, u16* __restrict__ d4,   // wo      65536
    const float* __restrict__ s5, u16* __restrict__ d5,   // w1     262144
    const float* __restrict__ s6, u16* __restrict__ d6)   // w2     262144
{
  const int total = 2359296;
  int i = blockIdx.x * 256 + threadIdx.x;
  const int stride = gridDim.x * 256;
  for (; i < total; i += stride) {
    const float* s; u16* d; int loc;
    if (i < 524288)        { s = s0; d = d0; loc = i; }
    else if (i < 1572864)  { s = s1; d = d1; loc = i - 524288; }
    else if (i < 1638400)  { s = s2; d = d2; loc = i - 1572864; }
    else if (i < 1769472)  { s = s3; d = d3; loc = i - 1638400; }
    else if (i < 1835008)  { s = s4; d = d4; loc = i - 1769472; }
    else if (i < 2097152)  { s = s5; d = d5; loc = i - 1835008; }
    else                   { s = s6; d = d6; loc = i - 2097152; }
    float4 v = reinterpret_cast<const float4*>(s)[loc];
    ushort4 o;
    o.x = f2bf(v.x); o.y = f2bf(v.y); o.z = f2bf(v.z); o.w = f2bf(v.w);
    reinterpret_cast<ushort4*>(d)[loc] = o;
  }
}

// ---------------- mask -> packed bits (bool-bytes / int32 / float32), vectorized ----------------
__global__ __launch_bounds__(256) void mask_bits_kernel(const void* __restrict__ mraw,
                                                        unsigned* __restrict__ mout, int n) {
  __shared__ int mode;
  const int t = threadIdx.x;
  const int* mi = (const int*)mraw;
  if (t == 0) mode = 0;
  __syncthreads();
  int local = 0;
  for (int i = t; i < 2048; i += 256) {
    unsigned v = (unsigned)mi[i];
    if (v == 0x3F800000u) { local = 2; break; }
    if (v > 1u) local = 1;
  }
  atomicMax(&mode, local);
  __syncthreads();
  const int m = mode;
  const uint4* m4 = (const uint4*)mraw;
  const int nw = n / 32;
  for (int wk = t; wk < nw; wk += 256) {
    unsigned bits = 0;
    if (m == 1) {
      uint4 a = m4[wk * 2], b = m4[wk * 2 + 1];
      unsigned ww[8] = {a.x, a.y, a.z, a.w, b.x, b.y, b.z, b.w};
#pragma unroll
      for (int k = 0; k < 8; ++k)
#pragma unroll
        for (int j = 0; j < 4; ++j)
          bits |= (((ww[k] >> (j * 8)) & 0xFFu) ? 1u : 0u) << (k * 4 + j);
    } else {
#pragma unroll
      for (int k = 0; k < 8; ++k) {
        uint4 a = m4[wk * 8 + k];
        unsigned t0 = (m == 2) ? ((a.x << 1) ? 1u : 0u) : (a.x ? 1u : 0u);
        unsigned t1 = (m == 2) ? ((a.y << 1) ? 1u : 0u) : (a.y ? 1u : 0u);
        unsigned t2 = (m == 2) ? ((a.z << 1) ? 1u : 0u) : (a.z ? 1u : 0u);
        unsigned t3 = (m == 2) ? ((a.w << 1) ? 1u : 0u) : (a.w ? 1u : 0u);
        bits |= (t0 | (t1 << 1) | (t2 << 2) | (t3 << 3)) << (k * 4);
      }
    }
    mout[wk] = bits;
  }
}

// ---------------- C = epilogue(A @ B^T), 128x128 tile, dbuf (for KV, FF1) ----------------
// EPI: 0 = bf16, 2 = bias+relu -> bf16
template<int EPI>
__global__ __launch_bounds__(256) void gemm_bt(
    const u16* __restrict__ A, const u16* __restrict__ B, void* __restrict__ Cv,
    const float* __restrict__ bias,
    int M, int N, int K, int lda, int ldb, int ldc)
{
  __shared__ u16 As[2][128 * 32];
  __shared__ u16 Bs[2][128 * 32];
  const int t = threadIdx.x;
  const int l = t & 63;
  const int w = t >> 6;
  const int wr = w >> 1, wc = w & 1;
  const int m0 = blockIdx.y * 128, n0 = blockIdx.x * 128;

  floatx4 acc[4][4];
#pragma unroll
  for (int m = 0; m < 4; ++m)
#pragma unroll
    for (int n = 0; n < 4; ++n)
      acc[m][n] = (floatx4){0.f, 0.f, 0.f, 0.f};

  const int row_st = t >> 2;
  const int kcol = (t & 3) * 8;

  auto stage = [&](int buf, int kt) {
#pragma unroll
    for (int c = 0; c < 2; ++c) {
      const int rA = m0 + c * 64 + row_st;
      const int rB = n0 + c * 64 + row_st;
      const int li = (c * 256 + t) * 8;
      __builtin_amdgcn_global_load_lds(
          (const AS1 void*)(A + (long)rA * lda + kt + kcol),
          (AS3 void*)(As[buf] + li), 16, 0, 0);
      __builtin_amdgcn_global_load_lds(
          (const AS1 void*)(B + (long)rB * ldb + kt + kcol),
          (AS3 void*)(Bs[buf] + li), 16, 0, 0);
    }
  };

  stage(0, 0);
  __syncthreads();
  int cur = 0;
  for (int kt = 0; kt < K; kt += 32) {
    if (kt + 32 < K) stage(cur ^ 1, kt + 32);

    short8 af[4], bf[4];
#pragma unroll
    for (int m = 0; m < 4; ++m)
      af[m] = *reinterpret_cast<const short8*>(&As[cur][(wr * 64 + m * 16 + (l & 15)) * 32 + (l >> 4) * 8]);
#pragma unroll
    for (int n = 0; n < 4; ++n)
      bf[n] = *reinterpret_cast<const short8*>(&Bs[cur][(wc * 64 + n * 16 + (l & 15)) * 32 + (l >> 4) * 8]);

    __builtin_amdgcn_s_setprio(1);
#pragma unroll
    for (int m = 0; m < 4; ++m)
#pragma unroll
      for (int n = 0; n < 4; ++n)
        acc[m][n] = __builtin_amdgcn_mfma_f32_16x16x32_bf16(af[m], bf[n], acc[m][n], 0, 0, 0);
    __builtin_amdgcn_s_setprio(0);

    __syncthreads();
    cur ^= 1;
  }

  const int cr = (l >> 4) * 4;
  const int cc = l & 15;
#pragma unroll
  for (int m = 0; m < 4; ++m) {
#pragma unroll
    for (int j = 0; j < 4; ++j) {
      const int row = m0 + wr * 64 + m * 16 + cr + j;
#pragma unroll
      for (int n = 0; n < 4; ++n) {
        const int col = n0 + wc * 64 + n * 16 + cc;
        float v = acc[m][n][j];
        long idx = (long)row * ldc + col;
        if constexpr (EPI == 0) {
          ((u16*)Cv)[idx] = f2bf(v);
        } else {
          v += bias[col]; v = fmaxf(v, 0.f);
          ((u16*)Cv)[idx] = f2bf(v);
        }
      }
    }
  }
}

// ---------------- 64x64-tile GEMM with fused epilogues (for N=512 GEMMs) ----------------
// 4 waves (2x2), per-wave 32x32 (2x2 frags). Grid (N/64, M/64) = 512 blocks at M=4096,N=512.
// EPI: 0 = *0.125 -> bf16 (Q); 1 = +res -> fp32 (Wo -> y1); 2 = +res+bias -> fp32 (FF2 -> y2)
template<int EPI>
__global__ __launch_bounds__(256) void gemm64(
    const u16* __restrict__ A, const u16* __restrict__ B, void* __restrict__ Cv,
    const float* __restrict__ res, const float* __restrict__ bias,
    int K, int lda, int ldb, int ldc)
{
  __shared__ u16 As[2][64 * 32];
  __shared__ u16 Bs[2][64 * 32];
  const int t = threadIdx.x;
  const int l = t & 63;
  const int w = t >> 6;
  const int wr = w >> 1, wc = w & 1;
  const int lo = l & 15, hi = l >> 4;
  const int m0 = blockIdx.y * 64, n0 = blockIdx.x * 64;

  floatx4 acc[2][2];
#pragma unroll
  for (int m = 0; m < 2; ++m)
#pragma unroll
    for (int n = 0; n < 2; ++n)
      acc[m][n] = (floatx4){0.f, 0.f, 0.f, 0.f};

  const int row_st = t >> 2;
  const int kcol = (t & 3) * 8;

  auto stage = [&](int buf, int kt) {
    __builtin_amdgcn_global_load_lds(
        (const AS1 void*)(A + (long)(m0 + row_st) * lda + kt + kcol),
        (AS3 void*)(As[buf] + t * 8), 16, 0, 0);
    __builtin_amdgcn_global_load_lds(
        (const AS1 void*)(B + (long)(n0 + row_st) * ldb + kt + kcol),
        (AS3 void*)(Bs[buf] + t * 8), 16, 0, 0);
  };

  stage(0, 0);
  __syncthreads();
  int cur = 0;
  for (int kt = 0; kt < K; kt += 32) {
    if (kt + 32 < K) stage(cur ^ 1, kt + 32);

    short8 af[2], bf[2];
#pragma unroll
    for (int m = 0; m < 2; ++m)
      af[m] = *reinterpret_cast<const short8*>(&As[cur][(wr * 32 + m * 16 + lo) * 32 + hi * 8]);
#pragma unroll
    for (int n = 0; n < 2; ++n)
      bf[n] = *reinterpret_cast<const short8*>(&Bs[cur][(wc * 32 + n * 16 + lo) * 32 + hi * 8]);

    __builtin_amdgcn_s_setprio(1);
#pragma unroll
    for (int m = 0; m < 2; ++m)
#pragma unroll
      for (int n = 0; n < 2; ++n)
        acc[m][n] = __builtin_amdgcn_mfma_f32_16x16x32_bf16(af[m], bf[n], acc[m][n], 0, 0, 0);
    __builtin_amdgcn_s_setprio(0);

    __syncthreads();
    cur ^= 1;
  }

  const int cr = hi * 4;
#pragma unroll
  for (int m = 0; m < 2; ++m) {
#pragma unroll
    for (int j = 0; j < 4; ++j) {
      const int row = m0 + wr * 32 + m * 16 + cr + j;
#pragma unroll
      for (int n = 0; n < 2; ++n) {
        const int col = n0 + wc * 32 + n * 16 + lo;
        float v = acc[m][n][j];
        long idx = (long)row * ldc + col;
        if constexpr (EPI == 0) {
          ((u16*)Cv)[idx] = f2bf(v * 0.125f);
        } else if constexpr (EPI == 1) {
          ((float*)Cv)[idx] = v + res[idx];
        } else {
          ((float*)Cv)[idx] = v + res[idx] + bias[col];
        }
      }
    }
  }
}

// ---------------- fused flash cross-attention v5 (v4 + defer-max T13) ----------------
__global__ __launch_bounds__(512, 4) void flash_attn_kernel(
    const u16* __restrict__ Qg, const u16* __restrict__ KVg,
    const u16* __restrict__ Vtg, const unsigned* __restrict__ mbits,
    u16* __restrict__ Og)
{
  __shared__ __align__(16) u16 KVbuf[2][2][64 * 64];  // 32 KB
  __shared__ __align__(16) u16 Ps[8][16 * 32];        // 8 KB
  __shared__ float mlred[2][2][64];                   // 1 KB
  __shared__ unsigned mw[64];

  const int t = threadIdx.x;
  const int l = t & 63;
  const int w = t >> 6;
  const int wr = w >> 1;       // q quarter (16 rows)
  const int wc = w & 1;        // s half (32 cols)
  const int lo = l & 15, hi = l >> 4;

  const int id = blockIdx.y * 16 + blockIdx.x;
  const int vid = (id & 7) * 64 + (id >> 3);
  const int qt = vid & 15, bh = vid >> 4;
  const int b = bh >> 3, h = bh & 7;

  const long qbase = ((long)b * 1024 + qt * 64) * 512 + h * 64;
  const long kbase = ((long)b * 2048) * 1024 + h * 64;
  const long vbase = ((long)bh * 64) * 2048;

  if (t < 64) mw[t] = mbits[b * 64 + t];

  auto stage_kv = [&](int buf, int soff) {
    const int s = t >> 3, c = t & 7;
    __builtin_amdgcn_global_load_lds(
        (const AS1 void*)(KVg + kbase + (long)(soff + s) * 1024 + ((c ^ (s & 7)) * 8)),
        (AS3 void*)(&KVbuf[buf][0][t * 8]), 16, 0, 0);
    __builtin_amdgcn_global_load_lds(
        (const AS1 void*)(Vtg + vbase + (long)s * 2048 + soff + ((c ^ (s & 7)) * 8)),
        (AS3 void*)(&KVbuf[buf][1][t * 8]), 16, 0, 0);
  };

  stage_kv(0, 0);

  short8 af[2];
#pragma unroll
  for (int ks = 0; ks < 2; ++ks)
    af[ks] = *reinterpret_cast<const short8*>(
        Qg + qbase + (long)(wr * 16 + lo) * 512 + ks * 32 + hi * 8);

  __syncthreads();

  floatx4 accO[4];
#pragma unroll
  for (int dn = 0; dn < 4; ++dn)
    accO[dn] = (floatx4){0.f, 0.f, 0.f, 0.f};
  float m_run = -1.0e30f, l_run = 0.f;

  int cur = 0;
  for (int it = 0; it < 32; ++it) {
    const int s0 = it * 64;
    if (it + 1 < 32) stage_kv(cur ^ 1, s0 + 64);

    // ---- St = mfma(K, Q): per wave 32s x 16q ----
    short8 bfr[2][2];
#pragma unroll
    for (int sn = 0; sn < 2; ++sn)
#pragma unroll
      for (int ks = 0; ks < 2; ++ks) {
        const int srow = wc * 32 + sn * 16 + lo;
        bfr[sn][ks] = *reinterpret_cast<const short8*>(
            &KVbuf[cur][0][srow * 64 + (((ks * 4 + hi) ^ (lo & 7)) * 8)]);
      }
    floatx4 sacc[2];
#pragma unroll
    for (int sn = 0; sn < 2; ++sn)
      sacc[sn] = (floatx4){0.f, 0.f, 0.f, 0.f};
    __builtin_amdgcn_s_setprio(1);
#pragma unroll
    for (int sn = 0; sn < 2; ++sn)
#pragma unroll
      for (int ks = 0; ks < 2; ++ks)
        sacc[sn] = __builtin_amdgcn_mfma_f32_16x16x32_bf16(bfr[sn][ks], af[ks], sacc[sn], 0, 0, 0);
    __builtin_amdgcn_s_setprio(0);

    // ---- mask (Q pre-scaled) ----
    const unsigned mword = mw[it * 2 + wc];
#pragma unroll
    for (int sn = 0; sn < 2; ++sn) {
      const unsigned nib = (mword >> (sn * 16)) >> (hi * 4);
#pragma unroll
      for (int j = 0; j < 4; ++j)
        if ((nib >> j) & 1u) sacc[sn][j] = -3.0e38f;
    }

    // ---- lane-local online softmax with defer-max (T13, THR=8) ----
    float mx = fmaxf(fmaxf(fmaxf(sacc[0][0], sacc[0][1]), fmaxf(sacc[0][2], sacc[0][3])),
                     fmaxf(fmaxf(sacc[1][0], sacc[1][1]), fmaxf(sacc[1][2], sacc[1][3])));
    mx = fmaxf(mx, __shfl_xor(mx, 16));
    mx = fmaxf(mx, __shfl_xor(mx, 32));
    if (!__all(mx <= m_run + 8.0f)) {       // wave-uniform; lanes w/o new max get al=1
      const float mn = fmaxf(m_run, mx);
      const float al = __expf(m_run - mn);
      m_run = mn;
      l_run *= al;
#pragma unroll
      for (int dn = 0; dn < 4; ++dn)
#pragma unroll
        for (int j = 0; j < 4; ++j)
          accO[dn][j] *= al;
    }

    // ---- exp, sum, pack, b64-write P ----
    {
      float s = 0.f;
      unsigned pw[2][2];
#pragma unroll
      for (int sn = 0; sn < 2; ++sn) {
        const float e0 = __expf(sacc[sn][0] - m_run);
        const float e1 = __expf(sacc[sn][1] - m_run);
        const float e2 = __expf(sacc[sn][2] - m_run);
        const float e3 = __expf(sacc[sn][3] - m_run);
        s += (e0 + e1) + (e2 + e3);
        pw[sn][0] = pack_bf2(e0, e1);
        pw[sn][1] = pack_bf2(e2, e3);
      }
      s += __shfl_xor(s, 16);
      s += __shfl_xor(s, 32);
      l_run += s;
#pragma unroll
      for (int sn = 0; sn < 2; ++sn) {
        uint2 wv; wv.x = pw[sn][0]; wv.y = pw[sn][1];
        *reinterpret_cast<uint2*>(&Ps[w][lo * 32 + (((sn * 4 + hi) ^ (lo & 7)) * 4)]) = wv;
      }
    }

    // ---- PV = mfma(V, P), K = 32 ----
    short8 va[4];
#pragma unroll
    for (int dn = 0; dn < 4; ++dn) {
      const int d = dn * 16 + lo;
      va[dn] = *reinterpret_cast<const short8*>(
          &KVbuf[cur][1][d * 64 + (((wc * 4 + hi) ^ (d & 7)) * 8)]);
    }
    short8 pb;
    {
      uint2 a = *reinterpret_cast<const uint2*>(&Ps[w][lo * 32 + (((2 * hi) ^ (lo & 7)) * 4)]);
      uint2 bq = *reinterpret_cast<const uint2*>(&Ps[w][lo * 32 + (((2 * hi + 1) ^ (lo & 7)) * 4)]);
      uint4 comb; comb.x = a.x; comb.y = a.y; comb.z = bq.x; comb.w = bq.y;
      __builtin_memcpy(&pb, &comb, 16);
    }
    __builtin_amdgcn_s_setprio(1);
#pragma unroll
    for (int dn = 0; dn < 4; ++dn)
      accO[dn] = __builtin_amdgcn_mfma_f32_16x16x32_bf16(va[dn], pb, accO[dn], 0, 0, 0);
    __builtin_amdgcn_s_setprio(0);

    __syncthreads();
    cur ^= 1;
  }

  // ---- epilogue: merge the 2 s-halves ----
  if (hi == 0) {
    const int q = wr * 16 + lo;
    mlred[wc][0][q] = m_run;
    mlred[wc][1][q] = l_run;
  }
  __syncthreads();
  float scal;
  {
    const int q = wr * 16 + lo;
    const float ms = fmaxf(mlred[0][0][q], mlred[1][0][q]);
    scal = __expf(m_run - ms);
  }
  float* Of = (float*)KVbuf;
  if (wc == 0) {
#pragma unroll
    for (int dn = 0; dn < 4; ++dn) {
      const int q = wr * 16 + lo;
      float4 v;
      v.x = accO[dn][0] * scal; v.y = accO[dn][1] * scal;
      v.z = accO[dn][2] * scal; v.w = accO[dn][3] * scal;
      *reinterpret_cast<float4*>(&Of[q * 64 + (((dn * 4 + hi) ^ (q & 15)) * 4)]) = v;
    }
  }
  __syncthreads();
  if (wc == 1) {
#pragma unroll
    for (int dn = 0; dn < 4; ++dn) {
      const int q = wr * 16 + lo;
      float4* pp = reinterpret_cast<float4*>(&Of[q * 64 + (((dn * 4 + hi) ^ (q & 15)) * 4)]);
      float4 v = *pp;
      v.x += accO[dn][0] * scal; v.y += accO[dn][1] * scal;
      v.z += accO[dn][2] * scal; v.w += accO[dn][3] * scal;
      *pp = v;
    }
  }
  __syncthreads();
  {
    const int q = t >> 3;
    const int dc = t & 7;
    const float m0 = mlred[0][0][q], m1 = mlred[1][0][q];
    const float ms = fmaxf(m0, m1);
    const float ls = mlred[0][1][q] * __expf(m0 - ms) + mlred[1][1][q] * __expf(m1 - ms);
    const float inv = 1.0f / ls;
    float4 v0 = *reinterpret_cast<const float4*>(&Of[q * 64 + (((dc * 2) ^ (q & 15)) * 4)]);
    float4 v1 = *reinterpret_cast<const float4*>(&Of[q * 64 + (((dc * 2 + 1) ^ (q & 15)) * 4)]);
    u16 ov[8];
    ov[0] = f2bf(v0.x * inv); ov[1] = f2bf(v0.y * inv);
    ov[2] = f2bf(v0.z * inv); ov[3] = f2bf(v0.w * inv);
    ov[4] = f2bf(v1.x * inv); ov[5] = f2bf(v1.y * inv);
    ov[6] = f2bf(v1.z * inv); ov[7] = f2bf(v1.w * inv);
    uint4 wv;
    __builtin_memcpy(&wv, ov, 16);
    *reinterpret_cast<uint4*>(Og + qbase + (long)q * 512 + dc * 8) = wv;
  }
}

// ---------------- layernorm over a single pre-summed fp32 buffer ----------------
template<bool WRITE_BF>
__global__ __launch_bounds__(64) void ln2_kernel(const float* __restrict__ y,
    const float* __restrict__ g, const float* __restrict__ be,
    float* __restrict__ xf, u16* __restrict__ xb) {
  const long base = (long)blockIdx.x * 512;
  const int t = threadIdx.x;
  float v[8]; float s = 0.f;
#pragma unroll
  for (int j = 0; j < 8; ++j) { int i = t + j * 64; v[j] = y[base + i]; s += v[j]; }
#pragma unroll
  for (int o = 32; o; o >>= 1) s += __shfl_xor(s, o);
  const float mu = s * (1.0f / 512.0f);
  float q2 = 0.f;
#pragma unroll
  for (int j = 0; j < 8; ++j) { float d = v[j] - mu; q2 += d * d; }
#pragma unroll
  for (int o = 32; o; o >>= 1) q2 += __shfl_xor(q2, o);
  const float rs = rsqrtf(q2 * (1.0f / 512.0f) + 1e-5f);
#pragma unroll
  for (int j = 0; j < 8; ++j) {
    int i = t + j * 64;
    float o = (v[j] - mu) * rs * g[i] + be[i];
    xf[base + i] = o;
    if (WRITE_BF) xb[base + i] = f2bf(o);
  }
}

// ---------------- V transpose: Vt[b][h][d][s] = KV[b*S+s][512 + h*64 + d] ----------------
__global__ __launch_bounds__(256) void transpose_v_kernel(const u16* __restrict__ KV,
                                                          u16* __restrict__ Vt) {
  __shared__ u16 tile[128 * 65];
  const int z = blockIdx.y;
  const int b = z >> 3, h = z & 7;
  const int s0 = blockIdx.x * 128;
  const int t = threadIdx.x;
#pragma unroll
  for (int k = 0; k < 32; ++k) {
    int i = k * 256 + t;
    int s = i >> 6, d = i & 63;
    tile[s * 65 + d] = KV[(long)(b * 2048 + s0 + s) * 1024 + 512 + h * 64 + d];
  }
  __syncthreads();
#pragma unroll
  for (int k = 0; k < 32; ++k) {
    int i = k * 256 + t;
    int d = i >> 7, sl = i & 127;
    Vt[((long)z * 64 + d) * 2048 + s0 + sl] = tile[sl * 65 + d];
  }
}

extern "C" void kernel_launch(void* const* d_in, const int* in_sizes, int n_in,
                              void* d_out, int out_size, void* d_ws, size_t ws_size,
                              hipStream_t stream) {
  const float* tgt    = (const float*)d_in[0];
  const float* memory = (const float*)d_in[1];
  const void*  maskraw= (const void*)d_in[2];
  const float* Wq  = (const float*)d_in[3];
  const float* Wkv = (const float*)d_in[4];
  const float* Wo  = (const float*)d_in[5];
  const float* W1  = (const float*)d_in[6];
  const float* b1  = (const float*)d_in[7];
  const float* W2  = (const float*)d_in[8];
  const float* b2  = (const float*)d_in[9];
  const float* g1  = (const float*)d_in[10];
  const float* be1 = (const float*)d_in[11];
  const float* g2  = (const float*)d_in[12];
  const float* be2 = (const float*)d_in[13];

  constexpr int B = 4, V = 1024, S = 2048, D = 512, H = 8, FF = 2048, hd = 64;
  const long BVD = (long)B * V * D;

  char* p = (char*)d_ws;
  auto alloc = [&](size_t bytes) -> void* {
    void* r = (void*)p; p += (bytes + 255) & ~(size_t)255; return r;
  };
  u16*  tgt_b = (u16*)alloc((size_t)BVD * 2);
  u16*  mem_b = (u16*)alloc((size_t)B * S * D * 2);
  u16*  wq_b  = (u16*)alloc((size_t)D * D * 2);
  u16*  wkv_b = (u16*)alloc((size_t)2 * D * D * 2);
  u16*  wo_b  = (u16*)alloc((size_t)D * D * 2);
  u16*  w1_b  = (u16*)alloc((size_t)FF * D * 2);
  u16*  w2_b  = (u16*)alloc((size_t)D * FF * 2);
  u16*  Qb    = (u16*)alloc((size_t)BVD * 2);
  u16*  KVb   = (u16*)alloc((size_t)B * S * 2 * D * 2);
  u16*  Vt    = (u16*)alloc((size_t)B * H * hd * S * 2);
  u16*  attn_b= (u16*)alloc((size_t)BVD * 2);
  float* y1   = (float*)alloc((size_t)BVD * 4);   // tgt + attn@Wo^T
  float* xf   = (float*)alloc((size_t)BVD * 4);
  u16*  xb    = (u16*)alloc((size_t)BVD * 2);
  u16*  hb    = (u16*)alloc((size_t)B * V * FF * 2);
  float* y2   = (float*)alloc((size_t)BVD * 4);   // xf + h@W2^T + b2
  unsigned* mbitsW = (unsigned*)alloc((size_t)(B * S / 32) * 4);

  cast_all_kernel<<<dim3(2048), 256, 0, stream>>>(
      tgt, tgt_b, memory, mem_b, Wq, wq_b, Wkv, wkv_b, Wo, wo_b, W1, w1_b, W2, w2_b);

  mask_bits_kernel<<<dim3(1), 256, 0, stream>>>(maskraw, mbitsW, B * S);

  // Q = (tgt @ Wq^T) * 0.125  : 64-tile, grid (8,64) = 512 blocks
  gemm64<0><<<dim3(D / 64, (B * V) / 64), 256, 0, stream>>>(
      tgt_b, wq_b, Qb, nullptr, nullptr, D, D, D, D);
  // KV = memory @ Wkv^T : 128-tile, grid (8,64)
  gemm_bt<0><<<dim3((2 * D) / 128, (B * S) / 128), 256, 0, stream>>>(
      mem_b, wkv_b, KVb, nullptr, B * S, 2 * D, D, D, D, 2 * D);
  // Vt[b][h][d][s]
  transpose_v_kernel<<<dim3(S / 128, B * H), 256, 0, stream>>>(KVb, Vt);

  // fused flash attention -> attn_b
  flash_attn_kernel<<<dim3(16, B * H), 512, 0, stream>>>(
      Qb, KVb, Vt, mbitsW, attn_b);

  // y1 = tgt + attn @ Wo^T : fused residual, grid (8,64)
  gemm64<1><<<dim3(D / 64, (B * V) / 64), 256, 0, stream>>>(
      attn_b, wo_b, y1, tgt, nullptr, D, D, D, D);
  // x = LN(y1) -> xf (fp32) + xb (bf16)
  ln2_kernel<true><<<dim3(B * V), 64, 0, stream>>>(y1, g1, be1, xf, xb);
  // h = relu(x @ W1^T + b1) : 128-tile, grid (16,32)
  gemm_bt<2><<<dim3(FF / 128, (B * V) / 128), 256, 0, stream>>>(
      xb, w1_b, hb, b1, B * V, FF, D, D, D, FF);
  // y2 = xf + h @ W2^T + b2 : fused residual+bias, grid (8,64)
  gemm64<2><<<dim3(D / 64, (B * V) / 64), 256, 0, stream>>>(
      hb, w2_b, y2, xf, b2, FF, FF, FF, D);
  // out = LN(y2) -> fp32 d_out
  ln2_kernel<false><<<dim3(B * V), 64, 0, stream>>>(y2, g2, be2, (float*)d_out, nullptr);
}